// Round 1
// baseline (6222.489 us; speedup 1.0000x reference)
//
#include <hip/hip_runtime.h>
#include <cstdint>

#define HW 4096
#define CCH 128

// ======================= conv1x1 tiled GEMM =======================
// grid (64 position-tiles, B). block 256. out tile: 128 o x 64 p. K chunks of 32.
// mode 0: single input xa with Kreal channels
// mode 1: aux concat: edge(xa,128) seg(xb,128) pred_edge(xc,1) pred_seg(xd,20) -> 277
// mode 2: concat [xa(128), xb(128)] -> 256
// ep 0: out = acc + bias
// ep 1: out = (tin - mu)*rstd*gamma + acc + bias   (fused ADN)
__global__ __launch_bounds__(256) void conv1x1_k(
    const float* __restrict__ xa, const float* __restrict__ xb,
    const float* __restrict__ xc, const float* __restrict__ xd,
    const float* __restrict__ w, const float* __restrict__ bias,
    float* __restrict__ out,
    int Kreal, int nchunks, int mode, int ep,
    const float* __restrict__ gammabuf, const float* __restrict__ stats,
    const float* __restrict__ tin)
{
    __shared__ float Xs[32][64];
    __shared__ float Ws[128][33];   // +1 pad: 4 ty-groups hit 4 distinct banks
    int b = blockIdx.y, p0 = blockIdx.x * 64;
    int t = threadIdx.x;
    int tx = t & 15, ty = t >> 4;
    float acc[8][4];
#pragma unroll
    for (int j = 0; j < 8; ++j)
#pragma unroll
        for (int i = 0; i < 4; ++i) acc[j][i] = 0.f;

    for (int ch = 0; ch < nchunks; ++ch) {
        int k0 = ch * 32;
        // stage W chunk: 128 x 32
#pragma unroll
        for (int i = 0; i < 16; ++i) {
            int idx = t + i * 256;
            int o = idx >> 5, kk = idx & 31;
            int kg = k0 + kk;
            Ws[o][kk] = (kg < Kreal) ? w[(size_t)o * Kreal + kg] : 0.f;
        }
        // stage X chunk: 32 x 64 positions
#pragma unroll
        for (int i = 0; i < 8; ++i) {
            int idx = t + i * 256;
            int kk = idx >> 6, p = idx & 63;
            int kg = k0 + kk;
            float v = 0.f;
            if (mode == 0) {
                if (kg < Kreal) v = xa[((size_t)b * Kreal + kg) * HW + p0 + p];
            } else if (mode == 1) {
                if (kg < 128)       v = xa[((size_t)b * 128 + kg) * HW + p0 + p];
                else if (kg < 256)  v = xb[((size_t)b * 128 + (kg - 128)) * HW + p0 + p];
                else if (kg == 256) v = xc[(size_t)b * HW + p0 + p];
                else if (kg < 277)  v = xd[((size_t)b * 20 + (kg - 257)) * HW + p0 + p];
            } else {
                if (kg < 128) v = xa[((size_t)b * 128 + kg) * HW + p0 + p];
                else          v = xb[((size_t)b * 128 + (kg - 128)) * HW + p0 + p];
            }
            Xs[kk][p] = v;
        }
        __syncthreads();
#pragma unroll
        for (int kk = 0; kk < 32; ++kk) {
            float xv[4];
#pragma unroll
            for (int i = 0; i < 4; ++i) xv[i] = Xs[kk][tx + 16 * i];
#pragma unroll
            for (int j = 0; j < 8; ++j) {
                float wv = Ws[ty * 8 + j][kk];
#pragma unroll
                for (int i = 0; i < 4; ++i) acc[j][i] += wv * xv[i];
            }
        }
        __syncthreads();
    }
    float mu = 0.f, rstd = 1.f;
    if (ep == 1) { mu = stats[b * 2]; rstd = stats[b * 2 + 1]; }
#pragma unroll
    for (int j = 0; j < 8; ++j) {
        int o = ty * 8 + j;
        float bb = bias[o];
#pragma unroll
        for (int i = 0; i < 4; ++i) {
            int p = p0 + tx + 16 * i;
            size_t off = ((size_t)b * CCH + o) * HW + p;
            float v = acc[j][i] + bb;
            if (ep == 1) {
                float tv = tin[off];
                v = (tv - mu) * rstd * gammabuf[off] + v;
            }
            out[off] = v;
        }
    }
}

// ======================= LayerNorm stats (per batch over C*H*W) =======================
__global__ __launch_bounds__(256) void lnstats_k(const float* __restrict__ in, float* __restrict__ stats)
{
    int b = blockIdx.x;
    int t = threadIdx.x;
    const float* p = in + (size_t)b * 524288;
    float s = 0.f, ss = 0.f;
    for (int i = t; i < 524288; i += 256) {
        float v = p[i];
        s += v; ss += v * v;
    }
#pragma unroll
    for (int o = 32; o >= 1; o >>= 1) { s += __shfl_xor(s, o); ss += __shfl_xor(ss, o); }
    __shared__ float rs[4], rss[4];
    int wv = t >> 6;
    if ((t & 63) == 0) { rs[wv] = s; rss[wv] = ss; }
    __syncthreads();
    if (t == 0) {
        s = rs[0] + rs[1] + rs[2] + rs[3];
        ss = rss[0] + rss[1] + rss[2] + rss[3];
        float mean = s * (1.f / 524288.f);
        float var = ss * (1.f / 524288.f) - mean * mean;
        var = fmaxf(var, 0.f);
        stats[b * 2] = mean;
        stats[b * 2 + 1] = rsqrtf(var + 1e-5f);
    }
}

// ======================= patch extraction =======================
// half 0: ph=2, N=1024, D=256 ; half 1: ph=4, N=256, D=1024. 16*N*D = 2^22 elems.
// trans=0: dst[(b*N+n)*D+f] ; trans=1: dst[(b*D+f)*N+n]
__global__ __launch_bounds__(256) void extract_k(const float* __restrict__ src, float* __restrict__ dst,
                                                 int half, int trans)
{
    int tid = blockIdx.x * 256 + threadIdx.x;
    int lph = half ? 2 : 1;
    int lD = half ? 10 : 8;
    int lN = half ? 8 : 10;
    int lo = half ? 4 : 5;
    int ch0 = half ? 64 : 0;
    int b = tid >> 18;
    int f, n;
    if (trans) { n = tid & ((1 << lN) - 1); f = (tid >> lN) & ((1 << lD) - 1); }
    else       { f = tid & ((1 << lD) - 1); n = (tid >> lD) & ((1 << lN) - 1); }
    int pm = (1 << lph) - 1;
    int c = f >> (2 * lph);
    int py = (f >> lph) & pm;
    int px = f & pm;
    int ohi = n >> lo, owi = n & ((1 << lo) - 1);
    int sp = ((ohi << lph) + py) * 64 + (owi << lph) + px;
    dst[tid] = src[((size_t)b * CCH + ch0 + c) * HW + sp];
}

// ======================= attention, patch 2x2 (half 0): N=1024, D=256 =======================
// grid (128 q-tiles of 8, B). block 256.
__global__ __launch_bounds__(256) void attn2_k(const float* __restrict__ Qp, const float* __restrict__ KT,
                                               const float* __restrict__ Vp, const float* __restrict__ x,
                                               float* __restrict__ mid)
{
    __shared__ float smem[2048 + 8 * 1024];   // Qs/Vs (8KB) + S (32KB)
    float* Qs = smem;
    float* S = smem + 2048;
    int b = blockIdx.y;
    int q0 = blockIdx.x * 8;
    int t = threadIdx.x;
#pragma unroll
    for (int i = 0; i < 8; ++i) {
        int idx = t + i * 256;
        Qs[idx] = Qp[((size_t)b * 1024 + q0 + (idx >> 8)) * 256 + (idx & 255)];
    }
    __syncthreads();
    const float scale = 0.0625f;  // 1/sqrt(256)
    // phase A: scores
    for (int i = 0; i < 4; ++i) {
        int m = i * 256 + t;
        float acc[8];
#pragma unroll
        for (int q = 0; q < 8; ++q) acc[q] = 0.f;
#pragma unroll 4
        for (int f = 0; f < 256; ++f) {
            float kv = KT[((size_t)b * 256 + f) * 1024 + m];
#pragma unroll
            for (int q = 0; q < 8; ++q) acc[q] += Qs[q * 256 + f] * kv;
        }
#pragma unroll
        for (int q = 0; q < 8; ++q) S[q * 1024 + m] = acc[q] * scale;
    }
    __syncthreads();
    // phase B: softmax rows (8 rows x 1024, 32 lanes per row)
    {
        int q = t >> 5, j = t & 31;
        float mx = -1e30f;
        for (int i = 0; i < 32; ++i) mx = fmaxf(mx, S[q * 1024 + j + 32 * i]);
#pragma unroll
        for (int o = 16; o >= 1; o >>= 1) mx = fmaxf(mx, __shfl_xor(mx, o));
        float sum = 0.f;
        for (int i = 0; i < 32; ++i) {
            float e = expf(S[q * 1024 + j + 32 * i] - mx);
            S[q * 1024 + j + 32 * i] = e;
            sum += e;
        }
#pragma unroll
        for (int o = 16; o >= 1; o >>= 1) sum += __shfl_xor(sum, o);
        float inv = 1.f / sum;
        for (int i = 0; i < 32; ++i) S[q * 1024 + j + 32 * i] *= inv;
    }
    __syncthreads();
    // phase C: P @ V, V staged in LDS tiles of 8 keys
    {
        int q = t >> 5, j = t & 31;
        float acc[8];
#pragma unroll
        for (int i = 0; i < 8; ++i) acc[i] = 0.f;
        float* Vs = smem;  // reuse Qs region: 8 x 256
        for (int tile = 0; tile < 128; ++tile) {
            __syncthreads();
#pragma unroll
            for (int i = 0; i < 8; ++i) {
                int idx = t + i * 256;
                Vs[idx] = Vp[((size_t)b * 1024 + tile * 8 + (idx >> 8)) * 256 + (idx & 255)];
            }
            __syncthreads();
#pragma unroll
            for (int mm = 0; mm < 8; ++mm) {
                float pp = S[q * 1024 + tile * 8 + mm];
#pragma unroll
                for (int i = 0; i < 8; ++i) acc[i] += pp * Vs[mm * 256 + j + 32 * i];
            }
        }
        int n = q0 + q;
        int ohi = n >> 5, owi = n & 31;
#pragma unroll
        for (int i = 0; i < 8; ++i) {
            int f = j + 32 * i;
            int c = f >> 2, py = (f >> 1) & 1, px = f & 1;
            size_t off = ((size_t)b * CCH + c) * HW + (ohi * 2 + py) * 64 + owi * 2 + px;
            mid[off] = x[off] + acc[i];
        }
    }
}

// ======================= attention, patch 4x4 (half 1): N=256, D=1024 =======================
// grid (32 q-tiles of 8, B). block 256.
__global__ __launch_bounds__(256) void attn4_k(const float* __restrict__ Qp, const float* __restrict__ KT,
                                               const float* __restrict__ Vp, const float* __restrict__ x,
                                               float* __restrict__ mid)
{
    __shared__ float smem[8192 + 2048];   // Qs/Vs (32KB) + S (8KB)
    float* Qs = smem;
    float* S = smem + 8192;
    int b = blockIdx.y;
    int q0 = blockIdx.x * 8;
    int t = threadIdx.x;
#pragma unroll
    for (int i = 0; i < 32; ++i) {
        int idx = t + i * 256;
        Qs[idx] = Qp[((size_t)b * 256 + q0 + (idx >> 10)) * 1024 + (idx & 1023)];
    }
    __syncthreads();
    const float scale = 0.03125f;  // 1/sqrt(1024)
    // phase A: each thread owns one key column m=t
    {
        int m = t;
        float acc[8];
#pragma unroll
        for (int q = 0; q < 8; ++q) acc[q] = 0.f;
#pragma unroll 4
        for (int f = 0; f < 1024; ++f) {
            float kv = KT[((size_t)b * 1024 + f) * 256 + m];
#pragma unroll
            for (int q = 0; q < 8; ++q) acc[q] += Qs[q * 1024 + f] * kv;
        }
#pragma unroll
        for (int q = 0; q < 8; ++q) S[q * 256 + m] = acc[q] * scale;
    }
    __syncthreads();
    // phase B: softmax (8 rows x 256, 32 lanes per row)
    {
        int q = t >> 5, j = t & 31;
        float mx = -1e30f;
        for (int i = 0; i < 8; ++i) mx = fmaxf(mx, S[q * 256 + j + 32 * i]);
#pragma unroll
        for (int o = 16; o >= 1; o >>= 1) mx = fmaxf(mx, __shfl_xor(mx, o));
        float sum = 0.f;
        for (int i = 0; i < 8; ++i) {
            float e = expf(S[q * 256 + j + 32 * i] - mx);
            S[q * 256 + j + 32 * i] = e;
            sum += e;
        }
#pragma unroll
        for (int o = 16; o >= 1; o >>= 1) sum += __shfl_xor(sum, o);
        float inv = 1.f / sum;
        for (int i = 0; i < 8; ++i) S[q * 256 + j + 32 * i] *= inv;
    }
    __syncthreads();
    // phase C
    {
        int q = t >> 5, j = t & 31;
        float acc[32];
#pragma unroll
        for (int i = 0; i < 32; ++i) acc[i] = 0.f;
        float* Vs = smem;  // 8 x 1024, reuse Qs
        for (int tile = 0; tile < 32; ++tile) {
            __syncthreads();
#pragma unroll
            for (int i = 0; i < 32; ++i) {
                int idx = t + i * 256;
                Vs[idx] = Vp[((size_t)b * 256 + tile * 8 + (idx >> 10)) * 1024 + (idx & 1023)];
            }
            __syncthreads();
#pragma unroll
            for (int mm = 0; mm < 8; ++mm) {
                float pp = S[q * 256 + tile * 8 + mm];
#pragma unroll
                for (int i = 0; i < 32; ++i) acc[i] += pp * Vs[mm * 1024 + j + 32 * i];
            }
        }
        int n = q0 + q;
        int ohi = n >> 4, owi = n & 15;
#pragma unroll
        for (int i = 0; i < 32; ++i) {
            int f = j + 32 * i;
            int c = f >> 4, py = (f >> 2) & 3, px = f & 3;
            size_t off = ((size_t)b * CCH + 64 + c) * HW + (ohi * 4 + py) * 64 + owi * 4 + px;
            mid[off] = x[off] + acc[i];
        }
    }
}

// ======================= conv3x3 =======================
// grid (64 rows, B). block 256. out tile: 128 o x 64 x (one row).
// EP 0: tanh ; EP 1: exact gelu ; EP 2: out = mid*g3 + acc+bias
template <int DIL, int EP>
__global__ __launch_bounds__(256) void conv3x3_k(
    const float* __restrict__ in, const float* __restrict__ w,
    const float* __restrict__ bias, float* __restrict__ out,
    const float* __restrict__ mid, const float* __restrict__ g3)
{
    constexpr int WT = 64 + 2 * DIL;
    __shared__ float Xs[8][3][WT];
    __shared__ float Ws[128 * 73];   // [o][i(8)*9+tap], stride 73 for bank spread
    int b = blockIdx.y, y = blockIdx.x;
    int t = threadIdx.x, tx = t & 15, ty = t >> 4;
    float acc[8][4];
#pragma unroll
    for (int j = 0; j < 8; ++j)
#pragma unroll
        for (int i = 0; i < 4; ++i) acc[j][i] = 0.f;

    for (int ch = 0; ch < 16; ++ch) {
        int k0 = ch * 8;
        // weights: 128 o x 8 i x 9 taps (contiguous 72-float runs per o)
#pragma unroll
        for (int i = 0; i < 36; ++i) {
            int idx = t + i * 256;
            int o = idx / 72, r = idx - o * 72;
            Ws[o * 73 + r] = w[(size_t)o * 1152 + k0 * 9 + r];
        }
        // inputs: 8 ch x 3 rows x WT cols with zero padding
        constexpr int TOT = 8 * 3 * WT;
        for (int idx = t; idx < TOT; idx += 256) {
            int kk = idx / (3 * WT);
            int rem = idx - kk * (3 * WT);
            int ky = rem / WT;
            int xx = rem - ky * WT;
            int iy = y + (ky - 1) * DIL;
            int ix = xx - DIL;
            float v = 0.f;
            if (iy >= 0 && iy < 64 && ix >= 0 && ix < 64)
                v = in[((size_t)b * CCH + k0 + kk) * HW + iy * 64 + ix];
            Xs[kk][ky][xx] = v;
        }
        __syncthreads();
        for (int ii = 0; ii < 8; ++ii) {
#pragma unroll
            for (int ky = 0; ky < 3; ++ky)
#pragma unroll
                for (int kx = 0; kx < 3; ++kx) {
                    float wv[8];
#pragma unroll
                    for (int j = 0; j < 8; ++j) wv[j] = Ws[(ty * 8 + j) * 73 + ii * 9 + ky * 3 + kx];
#pragma unroll
                    for (int i = 0; i < 4; ++i) {
                        float xv = Xs[ii][ky][tx + 16 * i + kx * DIL];
#pragma unroll
                        for (int j = 0; j < 8; ++j) acc[j][i] += wv[j] * xv;
                    }
                }
        }
        __syncthreads();
    }
#pragma unroll
    for (int j = 0; j < 8; ++j) {
        int o = ty * 8 + j;
        float bb = bias[o];
#pragma unroll
        for (int i = 0; i < 4; ++i) {
            int xc = tx + 16 * i;
            size_t off = ((size_t)b * CCH + o) * HW + y * 64 + xc;
            float v = acc[j][i] + bb;
            if (EP == 0) v = tanhf(v);
            else if (EP == 1) v = 0.5f * v * (1.f + erff(v * 0.70710678118654752f));
            else v = mid[off] * g3[off] + v;
            out[off] = v;
        }
    }
}

// ======================= launch =======================
extern "C" void kernel_launch(void* const* d_in, const int* in_sizes, int n_in,
                              void* d_out, int out_size, void* d_ws, size_t ws_size,
                              hipStream_t stream)
{
    const float* x    = (const float*)d_in[0];
    const float* edge = (const float*)d_in[1];
    const float* seg  = (const float*)d_in[2];
    const float* pe   = (const float*)d_in[3];
    const float* ps   = (const float*)d_in[4];
    const float* q_w  = (const float*)d_in[5];  const float* q_b  = (const float*)d_in[6];
    const float* k_w  = (const float*)d_in[7];  const float* k_b  = (const float*)d_in[8];
    const float* v_w  = (const float*)d_in[9];  const float* v_b  = (const float*)d_in[10];
    const float* d1_ew = (const float*)d_in[11]; const float* d1_eb = (const float*)d_in[12];
    const float* d1_sw = (const float*)d_in[13]; const float* d1_sb = (const float*)d_in[14];
    const float* d1_bw = (const float*)d_in[15]; const float* d1_bb = (const float*)d_in[16];
    const float* d2_ew = (const float*)d_in[17]; const float* d2_eb = (const float*)d_in[18];
    const float* d2_sw = (const float*)d_in[19]; const float* d2_sb = (const float*)d_in[20];
    const float* d2_bw = (const float*)d_in[21]; const float* d2_bb = (const float*)d_in[22];
    const float* sc_w  = (const float*)d_in[23]; const float* sc_b  = (const float*)d_in[24];
    const float* bi1_w = (const float*)d_in[25]; const float* bi1_b = (const float*)d_in[26];
    const float* bi2_w = (const float*)d_in[27]; const float* bi2_b = (const float*)d_in[28];

    const size_t U = (size_t)16 * 128 * 4096;   // one [B,C,H,W] fp32 tensor (8.39M floats)
    float* W0 = (float*)d_ws;
    float* W1 = W0 + U;
    float* W2 = W1 + U;
    float* W3 = W2 + U;
    float* W4 = W3 + U;
    float* stats = W4 + U;                      // 128 floats
    const size_t HP = (size_t)16 * 1024 * 256;  // per-half patched tensor size

    dim3 g64(64, 16), b256(256);

    // phase 1: a1, gamma1, q0/k0/v0, LN stats, fused ADN (in place)
    conv1x1_k<<<g64, b256, 0, stream>>>(edge, seg, pe, ps, d1_ew, d1_eb, W0, 277, 9, 1, 0, nullptr, nullptr, nullptr);
    conv1x1_k<<<g64, b256, 0, stream>>>(W0, nullptr, nullptr, nullptr, d1_sw, d1_sb, W1, 128, 4, 0, 0, nullptr, nullptr, nullptr);
    conv1x1_k<<<g64, b256, 0, stream>>>(x, nullptr, nullptr, nullptr, q_w, q_b, W2, 128, 4, 0, 0, nullptr, nullptr, nullptr);
    conv1x1_k<<<g64, b256, 0, stream>>>(x, nullptr, nullptr, nullptr, k_w, k_b, W3, 128, 4, 0, 0, nullptr, nullptr, nullptr);
    conv1x1_k<<<g64, b256, 0, stream>>>(x, nullptr, nullptr, nullptr, v_w, v_b, W4, 128, 4, 0, 0, nullptr, nullptr, nullptr);
    lnstats_k<<<16, 256, 0, stream>>>(W2, stats + 0);
    lnstats_k<<<16, 256, 0, stream>>>(W3, stats + 32);
    lnstats_k<<<16, 256, 0, stream>>>(W4, stats + 64);
    conv1x1_k<<<g64, b256, 0, stream>>>(W2, W0, nullptr, nullptr, d1_bw, d1_bb, W2, 256, 8, 2, 1, W1, stats + 0, W2);
    conv1x1_k<<<g64, b256, 0, stream>>>(W3, W0, nullptr, nullptr, d1_bw, d1_bb, W3, 256, 8, 2, 1, W1, stats + 32, W3);
    conv1x1_k<<<g64, b256, 0, stream>>>(W4, W0, nullptr, nullptr, d1_bw, d1_bb, W4, 256, 8, 2, 1, W1, stats + 64, W4);

    // phase 2: patch extraction (Qp->W0, KpT->W1, Vp->W2)
    extract_k<<<16384, 256, 0, stream>>>(W2, W0, 0, 0);
    extract_k<<<16384, 256, 0, stream>>>(W2, W0 + HP, 1, 0);
    extract_k<<<16384, 256, 0, stream>>>(W3, W1, 0, 1);
    extract_k<<<16384, 256, 0, stream>>>(W3, W1 + HP, 1, 1);
    extract_k<<<16384, 256, 0, stream>>>(W4, W2, 0, 0);
    extract_k<<<16384, 256, 0, stream>>>(W4, W2 + HP, 1, 0);

    // phase 3: window attention -> mid = x + attn (W3)
    attn2_k<<<dim3(128, 16), b256, 0, stream>>>(W0, W1, W2, x, W3);
    attn4_k<<<dim3(32, 16), b256, 0, stream>>>(W0 + HP, W1 + HP, W2 + HP, x, W3);

    // phase 4: second ADN -> o (W1)
    conv1x1_k<<<g64, b256, 0, stream>>>(edge, seg, pe, ps, d2_ew, d2_eb, W4, 277, 9, 1, 0, nullptr, nullptr, nullptr);
    conv1x1_k<<<g64, b256, 0, stream>>>(W4, nullptr, nullptr, nullptr, d2_sw, d2_sb, W0, 128, 4, 0, 0, nullptr, nullptr, nullptr);
    lnstats_k<<<16, 256, 0, stream>>>(W3, stats + 96);
    conv1x1_k<<<g64, b256, 0, stream>>>(W3, W4, nullptr, nullptr, d2_bw, d2_bb, W1, 256, 8, 2, 1, W0, stats + 96, W3);

    // phase 5: gamma = tanh(conv3x3(o)) -> W2 ; t = gelu(conv3x3_dil2(o)) -> W4
    conv3x3_k<1, 0><<<g64, b256, 0, stream>>>(W1, sc_w, sc_b, W2, nullptr, nullptr);
    conv3x3_k<2, 1><<<g64, b256, 0, stream>>>(W1, bi1_w, bi1_b, W4, nullptr, nullptr);

    // phase 6: out = mid * gamma + conv3x3(t)
    conv3x3_k<1, 2><<<g64, b256, 0, stream>>>(W4, bi2_w, bi2_b, (float*)d_out, W3, W2);
}

// Round 2
// 1055.856 us; speedup vs baseline: 5.8933x; 5.8933x over previous
//
#include <hip/hip_runtime.h>
#include <cstdint>

typedef unsigned short ushort_t;
typedef unsigned int uint_t;
typedef __attribute__((ext_vector_type(8))) short short8;   // 8 bf16 (4 VGPRs) - MFMA A/B frag
typedef __attribute__((ext_vector_type(4))) float f32x4;    // MFMA C/D frag

#define MFMA16(a, b, c) __builtin_amdgcn_mfma_f32_16x16x32_bf16((a), (b), (c), 0, 0, 0)
// LDS chunk swizzle: logical 16B-chunk c of row r stored at phys chunk SWZ(c,r).
// Chosen so ds_read_b128 (lanes = consecutive rows) and staging stores stay <=4-way.
#define SWZ(c, r) ((((c) + ((r) >> 2)) & 3))
#define INV_N 1.9073486328125e-6f  // 1/524288

__device__ __forceinline__ ushort_t f2bf(float f) {
    uint_t u = __builtin_bit_cast(uint_t, f);
    u += 0x7FFFu + ((u >> 16) & 1u);          // RNE
    return (ushort_t)(u >> 16);
}
__device__ __forceinline__ float bf2f(ushort_t h) {
    return __builtin_bit_cast(float, (uint_t)h << 16);
}
__device__ __forceinline__ uint_t pack2(float lo, float hi) {
    return (uint_t)f2bf(lo) | ((uint_t)f2bf(hi) << 16);
}

// ===================== weight prep: fp32 -> bf16, pad/transform =====================
// wbuf element offsets:
// qw 0, kw 16384, vw 32768, ew1 49152(128x288 pad), sw1 86016, bw1 102400(128x256),
// ew2 135168, sw2 172032, bw2 188416, sc_t 221184(9x128x128), bi1_t 368640, bi2_t 516096. tot 663552
__global__ __launch_bounds__(256) void prep_w(
    ushort_t* wb, const float* qw, const float* kw, const float* vw,
    const float* ew1, const float* sw1, const float* bw1,
    const float* ew2, const float* sw2, const float* bw2,
    const float* scw, const float* b1w, const float* b2w)
{
    int idx = blockIdx.x * 256 + threadIdx.x;
    if (idx >= 663552) return;
    float v;
    if (idx < 16384) v = qw[idx];
    else if (idx < 32768) v = kw[idx - 16384];
    else if (idx < 49152) v = vw[idx - 32768];
    else if (idx < 86016) { int j = idx - 49152, o = j / 288, k = j % 288; v = (k < 277) ? ew1[o * 277 + k] : 0.f; }
    else if (idx < 102400) v = sw1[idx - 86016];
    else if (idx < 135168) v = bw1[idx - 102400];
    else if (idx < 172032) { int j = idx - 135168, o = j / 288, k = j % 288; v = (k < 277) ? ew2[o * 277 + k] : 0.f; }
    else if (idx < 188416) v = sw2[idx - 172032];
    else if (idx < 221184) v = bw2[idx - 188416];
    else if (idx < 368640) { int j = idx - 221184, tap = j >> 14, r = (j >> 7) & 127, c = j & 127; v = scw[r * 1152 + c * 9 + tap]; }
    else if (idx < 516096) { int j = idx - 368640, tap = j >> 14, r = (j >> 7) & 127, c = j & 127; v = b1w[r * 1152 + c * 9 + tap]; }
    else { int j = idx - 516096, tap = j >> 14, r = (j >> 7) & 127, c = j & 127; v = b2w[r * 1152 + c * 9 + tap]; }
    wb[idx] = f2bf(v);
}

// ===================== aux concat fp32 -> bf16 [B][288][4096] (277 real + 11 zero) ==========
__global__ __launch_bounds__(256) void prep_aux(
    ushort_t* aux, const float* edge, const float* seg, const float* pe, const float* ps)
{
    int idx4 = blockIdx.x * 256 + threadIdx.x;   // 4 elems each; total 4718592
    if (idx4 >= 4718592) return;
    int b = idx4 / (288 * 1024);
    int rem = idx4 - b * (288 * 1024);
    int ch = rem >> 10;
    int p = (rem & 1023) << 2;
    float4 f = {0.f, 0.f, 0.f, 0.f};
    if (ch < 128)       f = *(const float4*)(edge + ((size_t)(b * 128 + ch) << 12) + p);
    else if (ch < 256)  f = *(const float4*)(seg + ((size_t)(b * 128 + ch - 128) << 12) + p);
    else if (ch == 256) f = *(const float4*)(pe + ((size_t)b << 12) + p);
    else if (ch < 277)  f = *(const float4*)(ps + ((size_t)(b * 20 + ch - 257) << 12) + p);
    uint2 u = {pack2(f.x, f.y), pack2(f.z, f.w)};
    *(uint2*)(aux + ((size_t)idx4 << 2)) = u;
}

// ===================== conv1x1-family MFMA GEMM =====================
// C[o=128][p=128-tile] = W[128,Ctot] * X[Ctot, p]; grid (32 p-tiles, 16 batch), 256 thr = 4 waves 2x2.
// B-source: b1 (fp32 if b1f32 else bf16, C1 channels); optional b2 (bf16, 128ch) for k>=128 concat.
// EP 0: v=acc+bias -> bf16 out[b,o,p] (+ stats atomics if slotW>=0)
// EP 1: -> f32 out
// EP 2: ADN: v=(tin_bf-mu)*rstd*gamma + acc+bias -> scatter to patched bf16 (SC 1=Qp,2=KT,3=Vp)
// EP 3: ADN: tin_f32 -> f32 out
__global__ __launch_bounds__(256) void gemm_conv(
    const void* b1, int b1f32, const ushort_t* b2,
    int Ctot, int NK, const ushort_t* wA, const float* bias,
    int EP, void* out, int SC,
    const ushort_t* tin_bf, const float* tin_f32, const float* gamma,
    float* stats, int slotR, int slotW)
{
    __shared__ char lds[16448];
    int b = blockIdx.y, bx = blockIdx.x;
    int t = threadIdx.x, lane = t & 63, w = t >> 6;
    int wm = w & 1, wn = w >> 1, lo = lane & 15, quad = lane >> 4;
    int C1 = b2 ? 128 : Ctot;

    f32x4 acc[4][4];
#pragma unroll
    for (int i = 0; i < 4; ++i)
#pragma unroll
        for (int j = 0; j < 4; ++j) acc[i][j] = (f32x4){0.f, 0.f, 0.f, 0.f};

    for (int ck = 0; ck < NK; ++ck) {
        int k0 = ck * 32;
        __syncthreads();
        // ---- stage A (weights) 128 x 32 bf16
#pragma unroll
        for (int s = t; s < 512; s += 256) {
            int r = s >> 2, c = s & 3;
            uint4 v = *(const uint4*)(wA + (size_t)r * Ctot + k0 + c * 8);
            *(uint4*)(lds + r * 64 + SWZ(c, r) * 16) = v;
        }
        // ---- stage B (activations) 32k x 128p, transposed to [p][k] bf16
#pragma unroll
        for (int s = t; s < 512; s += 256) {
            int p4 = (s & 31) << 2;
            int kp = s >> 5;                 // k-pair 0..15
            int kk = k0 + kp * 2;
            int gp = bx * 128 + p4;
            uint_t wv[4];
            if (b2 && kk >= 128) {
                const ushort_t* r0 = b2 + ((size_t)(b * 128 + (kk - 128)) << 12) + gp;
                ushort4 a0 = *(const ushort4*)r0;
                ushort4 a1 = *(const ushort4*)(r0 + 4096);
                wv[0] = (uint_t)a0.x | ((uint_t)a1.x << 16);
                wv[1] = (uint_t)a0.y | ((uint_t)a1.y << 16);
                wv[2] = (uint_t)a0.z | ((uint_t)a1.z << 16);
                wv[3] = (uint_t)a0.w | ((uint_t)a1.w << 16);
            } else if (b1f32) {
                const float* r0 = (const float*)b1 + ((size_t)(b * C1 + kk) << 12) + gp;
                float4 f0 = *(const float4*)r0;
                float4 f1 = *(const float4*)(r0 + 4096);
                wv[0] = pack2(f0.x, f1.x); wv[1] = pack2(f0.y, f1.y);
                wv[2] = pack2(f0.z, f1.z); wv[3] = pack2(f0.w, f1.w);
            } else {
                const ushort_t* r0 = (const ushort_t*)b1 + ((size_t)(b * C1 + kk) << 12) + gp;
                ushort4 a0 = *(const ushort4*)r0;
                ushort4 a1 = *(const ushort4*)(r0 + 4096);
                wv[0] = (uint_t)a0.x | ((uint_t)a1.x << 16);
                wv[1] = (uint_t)a0.y | ((uint_t)a1.y << 16);
                wv[2] = (uint_t)a0.z | ((uint_t)a1.z << 16);
                wv[3] = (uint_t)a0.w | ((uint_t)a1.w << 16);
            }
#pragma unroll
            for (int e = 0; e < 4; ++e) {
                int p = p4 + e;
                *(uint_t*)(lds + 8192 + p * 64 + SWZ(kp >> 2, p) * 16 + (kp & 3) * 4) = wv[e];
            }
        }
        __syncthreads();
        // ---- compute: 16 MFMA per wave
        short8 af[4];
#pragma unroll
        for (int mt = 0; mt < 4; ++mt) {
            int row = wm * 64 + mt * 16 + lo;
            af[mt] = *(const short8*)(lds + row * 64 + SWZ(quad, row) * 16);
        }
#pragma unroll
        for (int nt = 0; nt < 4; ++nt) {
            int n = wn * 64 + nt * 16 + lo;
            short8 bf = *(const short8*)(lds + 8192 + n * 64 + SWZ(quad, n) * 16);
#pragma unroll
            for (int mt = 0; mt < 4; ++mt) acc[mt][nt] = MFMA16(af[mt], bf, acc[mt][nt]);
        }
    }

    // ---- epilogue
    float mean = 0.f, rstd = 0.f;
    if (EP >= 2) {
        float s = stats[(slotR * 16 + b) * 2], ss = stats[(slotR * 16 + b) * 2 + 1];
        mean = s * INV_N;
        rstd = rsqrtf(fmaxf(ss * INV_N - mean * mean, 0.f) + 1e-5f);
    }
    float lsum = 0.f, lss = 0.f;
#pragma unroll
    for (int mt = 0; mt < 4; ++mt)
#pragma unroll
        for (int nt = 0; nt < 4; ++nt)
#pragma unroll
            for (int reg = 0; reg < 4; ++reg) {
                int oo = wm * 64 + mt * 16 + quad * 4 + reg;
                int pp = wn * 64 + nt * 16 + lo;
                int gp = bx * 128 + pp;
                size_t off = ((size_t)(b * 128 + oo) << 12) + gp;
                float v = acc[mt][nt][reg] + bias[oo];
                if (EP == 2) {
                    v += (bf2f(tin_bf[off]) - mean) * rstd * gamma[off];
                    int y = gp >> 6, xx = gp & 63;
                    size_t idx;
                    if (oo < 64) {
                        int n = ((y >> 1) << 5) | (xx >> 1);
                        int f = (oo << 2) | ((y & 1) << 1) | (xx & 1);
                        idx = (SC == 2) ? ((size_t)(b * 256 + f) * 1024 + n)
                                        : ((size_t)(b * 1024 + n) * 256 + f);
                    } else {
                        int c = oo - 64;
                        int n = ((y >> 2) << 4) | (xx >> 2);
                        int f = (c << 4) | ((y & 3) << 2) | (xx & 3);
                        idx = 4194304u + ((SC == 2) ? ((size_t)(b * 1024 + f) * 256 + n)
                                                    : ((size_t)(b * 256 + n) * 1024 + f));
                    }
                    ((ushort_t*)out)[idx] = f2bf(v);
                } else if (EP == 3) {
                    v += (tin_f32[off] - mean) * rstd * gamma[off];
                    ((float*)out)[off] = v;
                } else if (EP == 1) {
                    ((float*)out)[off] = v;
                } else {
                    ((ushort_t*)out)[off] = f2bf(v);
                    lsum += v; lss += v * v;
                }
            }
    if (EP == 0 && slotW >= 0) {
#pragma unroll
        for (int o2 = 32; o2 >= 1; o2 >>= 1) { lsum += __shfl_xor(lsum, o2); lss += __shfl_xor(lss, o2); }
        __syncthreads();
        float* red = (float*)lds;
        if (lane == 0) { red[w * 2] = lsum; red[w * 2 + 1] = lss; }
        __syncthreads();
        if (t == 0) {
            atomicAdd(&stats[(slotW * 16 + b) * 2], red[0] + red[2] + red[4] + red[6]);
            atomicAdd(&stats[(slotW * 16 + b) * 2 + 1], red[1] + red[3] + red[5] + red[7]);
        }
    }
}

// ===================== attention batched MFMA GEMM (QK^T and P*V) =====================
// C[row][col] = A[row,k] * B[k,col]; grid (Nb/128, M/128, 16).
// EP 0: v*scale -> bf16 S[b][row][col] ; EP 1: half0 mid scatter + stats ; EP 2: half1
__global__ __launch_bounds__(256) void gemm_attn(
    const ushort_t* A, size_t aBS, int Ka,
    const ushort_t* Bm, size_t bBS, int Nb,
    int NK, int EP, float scale,
    ushort_t* sout, size_t soBS,
    const float* x, float* mid, float* stats)
{
    __shared__ char lds[16448];
    int b = blockIdx.z, my = blockIdx.y, nx = blockIdx.x;
    int t = threadIdx.x, lane = t & 63, w = t >> 6;
    int wm = w & 1, wn = w >> 1, lo = lane & 15, quad = lane >> 4;

    f32x4 acc[4][4];
#pragma unroll
    for (int i = 0; i < 4; ++i)
#pragma unroll
        for (int j = 0; j < 4; ++j) acc[i][j] = (f32x4){0.f, 0.f, 0.f, 0.f};

    for (int ck = 0; ck < NK; ++ck) {
        int k0 = ck * 32;
        __syncthreads();
#pragma unroll
        for (int s = t; s < 512; s += 256) {
            int r = s >> 2, c = s & 3;
            uint4 v = *(const uint4*)(A + b * aBS + (size_t)(my * 128 + r) * Ka + k0 + c * 8);
            *(uint4*)(lds + r * 64 + SWZ(c, r) * 16) = v;
        }
#pragma unroll
        for (int s = t; s < 512; s += 256) {
            int p4 = (s & 31) << 2;
            int kp = s >> 5;
            int kk = k0 + kp * 2;
            const ushort_t* r0 = Bm + b * bBS + (size_t)kk * Nb + nx * 128 + p4;
            ushort4 a0 = *(const ushort4*)r0;
            ushort4 a1 = *(const ushort4*)(r0 + Nb);
            uint_t wv[4] = {(uint_t)a0.x | ((uint_t)a1.x << 16), (uint_t)a0.y | ((uint_t)a1.y << 16),
                            (uint_t)a0.z | ((uint_t)a1.z << 16), (uint_t)a0.w | ((uint_t)a1.w << 16)};
#pragma unroll
            for (int e = 0; e < 4; ++e) {
                int p = p4 + e;
                *(uint_t*)(lds + 8192 + p * 64 + SWZ(kp >> 2, p) * 16 + (kp & 3) * 4) = wv[e];
            }
        }
        __syncthreads();
        short8 af[4];
#pragma unroll
        for (int mt = 0; mt < 4; ++mt) {
            int row = wm * 64 + mt * 16 + lo;
            af[mt] = *(const short8*)(lds + row * 64 + SWZ(quad, row) * 16);
        }
#pragma unroll
        for (int nt = 0; nt < 4; ++nt) {
            int n = wn * 64 + nt * 16 + lo;
            short8 bf = *(const short8*)(lds + 8192 + n * 64 + SWZ(quad, n) * 16);
#pragma unroll
            for (int mt = 0; mt < 4; ++mt) acc[mt][nt] = MFMA16(af[mt], bf, acc[mt][nt]);
        }
    }

    float lsum = 0.f, lss = 0.f;
#pragma unroll
    for (int mt = 0; mt < 4; ++mt)
#pragma unroll
        for (int nt = 0; nt < 4; ++nt)
#pragma unroll
            for (int reg = 0; reg < 4; ++reg) {
                int rr = my * 128 + wm * 64 + mt * 16 + quad * 4 + reg;  // n (window)
                int cc = nx * 128 + wn * 64 + nt * 16 + lo;              // m or d
                float v = acc[mt][nt][reg];
                if (EP == 0) {
                    sout[b * soBS + (size_t)rr * Nb + cc] = f2bf(v * scale);
                } else {
                    size_t off;
                    if (EP == 1) {
                        int ohi = rr >> 5, owi = rr & 31;
                        int c = cc >> 2, py = (cc >> 1) & 1, px = cc & 1;
                        int sp = ((ohi << 1) + py) * 64 + (owi << 1) + px;
                        off = ((size_t)(b * 128 + c) << 12) + sp;
                    } else {
                        int ohi = rr >> 4, owi = rr & 15;
                        int c = 64 + (cc >> 4), py = (cc >> 2) & 3, px = cc & 3;
                        int sp = ((ohi << 2) + py) * 64 + (owi << 2) + px;
                        off = ((size_t)(b * 128 + c) << 12) + sp;
                    }
                    float vm = x[off] + v;
                    mid[off] = vm;
                    lsum += vm; lss += vm * vm;
                }
            }
    if (EP >= 1) {
#pragma unroll
        for (int o2 = 32; o2 >= 1; o2 >>= 1) { lsum += __shfl_xor(lsum, o2); lss += __shfl_xor(lss, o2); }
        __syncthreads();
        float* red = (float*)lds;
        if (lane == 0) { red[w * 2] = lsum; red[w * 2 + 1] = lss; }
        __syncthreads();
        if (t == 0) {
            atomicAdd(&stats[(3 * 16 + b) * 2], red[0] + red[2] + red[4] + red[6]);
            atomicAdd(&stats[(3 * 16 + b) * 2 + 1], red[1] + red[3] + red[5] + red[7]);
        }
    }
}

// ===================== softmax (in-place bf16 S -> P) =====================
// rows: 16384 of len 1024 (half0) then 4096 of len 256 (half1). 1 wave per row.
__global__ __launch_bounds__(256) void softmax_k(ushort_t* SP)
{
    int wid = blockIdx.x * 4 + (threadIdx.x >> 6);
    int lane = threadIdx.x & 63;
    ushort_t* row;
    int PL;
    if (wid < 16384) {
        row = SP + ((size_t)wid << 10);
        PL = 16;
    } else {
        int r2 = wid - 16384;
        row = SP + 16777216u + ((size_t)r2 << 8);
        PL = 4;
    }
    float v[16];
    float mx = -1e30f;
    for (int i = 0; i < PL; ++i) { v[i] = bf2f(row[lane + (i << 6)]); mx = fmaxf(mx, v[i]); }
#pragma unroll
    for (int o = 32; o >= 1; o >>= 1) mx = fmaxf(mx, __shfl_xor(mx, o));
    float sum = 0.f;
    for (int i = 0; i < PL; ++i) { v[i] = __expf(v[i] - mx); sum += v[i]; }
#pragma unroll
    for (int o = 32; o >= 1; o >>= 1) sum += __shfl_xor(sum, o);
    float inv = 1.f / sum;
    for (int i = 0; i < PL; ++i) row[lane + (i << 6)] = f2bf(v[i] * inv);
}

// ===================== conv3x3 implicit-GEMM MFMA =====================
// K = 128ch x 9 taps; p-tile = 2 image rows. 4 ch-chunks; Braw staged once per chunk,
// A (weights, [tap][o][ch] prepped) staged per ky (3 kx at once).
// EP 0: tanh -> f32 ; EP 1: exact gelu -> f32 ; EP 2: mid*gam + acc+bias -> f32
template <int DIL, int EP>
__global__ __launch_bounds__(256) void conv3x3_mfma(
    const float* __restrict__ in, const ushort_t* __restrict__ wt, const float* __restrict__ bias,
    float* __restrict__ out, const float* __restrict__ mid, const float* __restrict__ gam)
{
    constexpr int NR = 2 + 2 * DIL;
    __shared__ char lds[24576 + NR * 68 * 64];
    char* Braw = lds + 24576;
    int b = blockIdx.y;
    int y0 = blockIdx.x * 2;
    int t = threadIdx.x, lane = t & 63, w = t >> 6;
    int wm = w & 1, wn = w >> 1, lo = lane & 15, quad = lane >> 4;

    f32x4 acc[4][4];
#pragma unroll
    for (int i = 0; i < 4; ++i)
#pragma unroll
        for (int j = 0; j < 4; ++j) acc[i][j] = (f32x4){0.f, 0.f, 0.f, 0.f};

    for (int cc = 0; cc < 4; ++cc) {
        __syncthreads();
        // stage raw input rows [NR][68 cols][32 ch] bf16 (zero-padded)
        constexpr int NSLOT = NR * 17 * 16;
        for (int s = t; s < NSLOT; s += 256) {
            int kp = s & 15;
            int rem = s >> 4;
            int xq = rem % 17, rr = rem / 17;
            int kk = kp * 2;
            int xx = xq * 4;
            int ys = y0 - DIL + rr;
            const float* src0 = in + ((size_t)(b * 128 + cc * 32 + kk) << 12) + ys * 64;
            float f0[4], f1[4];
#pragma unroll
            for (int e = 0; e < 4; ++e) {
                int ix = xx + e - DIL;
                bool ok = (ys >= 0) && (ys < 64) && (ix >= 0) && (ix < 64);
                f0[e] = ok ? src0[ix] : 0.f;
                f1[e] = ok ? src0[4096 + ix] : 0.f;
            }
#pragma unroll
            for (int e = 0; e < 4; ++e) {
                int pr = rr * 68 + xx + e;
                *(uint_t*)(Braw + pr * 64 + SWZ(kk >> 3, pr) * 16 + ((kk & 7) >> 1) * 4) = pack2(f0[e], f1[e]);
            }
        }
        for (int ky = 0; ky < 3; ++ky) {
            __syncthreads();
            // stage A for taps (ky, kx=0..2): 3 x 128 x 32
            for (int s = t; s < 1536; s += 256) {
                int kx = s >> 9, r = (s >> 2) & 127, c = s & 3;
                uint4 v = *(const uint4*)(wt + ((size_t)((ky * 3 + kx) * 128 + r) << 7) + cc * 32 + c * 8);
                *(uint4*)(lds + kx * 8192 + r * 64 + SWZ(c, r) * 16) = v;
            }
            __syncthreads();
#pragma unroll
            for (int kx = 0; kx < 3; ++kx) {
                short8 af[4];
#pragma unroll
                for (int mt = 0; mt < 4; ++mt) {
                    int row = wm * 64 + mt * 16 + lo;
                    af[mt] = *(const short8*)(lds + kx * 8192 + row * 64 + SWZ(quad, row) * 16);
                }
#pragma unroll
                for (int nt = 0; nt < 4; ++nt) {
                    int n = wn * 64 + nt * 16 + lo;
                    int pr = ((n >> 6) + ky * DIL) * 68 + (n & 63) + kx * DIL;
                    short8 bf = *(const short8*)(Braw + pr * 64 + SWZ(quad, pr) * 16);
#pragma unroll
                    for (int mt = 0; mt < 4; ++mt) acc[mt][nt] = MFMA16(af[mt], bf, acc[mt][nt]);
                }
            }
        }
    }
#pragma unroll
    for (int mt = 0; mt < 4; ++mt)
#pragma unroll
        for (int nt = 0; nt < 4; ++nt)
#pragma unroll
            for (int reg = 0; reg < 4; ++reg) {
                int oo = wm * 64 + mt * 16 + quad * 4 + reg;
                int pp = wn * 64 + nt * 16 + lo;
                int sp = (y0 + (pp >> 6)) * 64 + (pp & 63);
                size_t off = ((size_t)(b * 128 + oo) << 12) + sp;
                float v = acc[mt][nt][reg] + bias[oo];
                if (EP == 0) v = tanhf(v);
                else if (EP == 1) v = 0.5f * v * (1.f + erff(v * 0.70710678118654752f));
                else v = mid[off] * gam[off] + v;
                out[off] = v;
            }
}

// ===================== launch =====================
extern "C" void kernel_launch(void* const* d_in, const int* in_sizes, int n_in,
                              void* d_out, int out_size, void* d_ws, size_t ws_size,
                              hipStream_t stream)
{
    const float* x    = (const float*)d_in[0];
    const float* edge = (const float*)d_in[1];
    const float* seg  = (const float*)d_in[2];
    const float* pe   = (const float*)d_in[3];
    const float* ps   = (const float*)d_in[4];
    const float* q_w  = (const float*)d_in[5];  const float* q_b  = (const float*)d_in[6];
    const float* k_w  = (const float*)d_in[7];  const float* k_b  = (const float*)d_in[8];
    const float* v_w  = (const float*)d_in[9];  const float* v_b  = (const float*)d_in[10];
    const float* d1_ew = (const float*)d_in[11]; const float* d1_eb = (const float*)d_in[12];
    const float* d1_sw = (const float*)d_in[13]; const float* d1_sb = (const float*)d_in[14];
    const float* d1_bw = (const float*)d_in[15]; const float* d1_bb = (const float*)d_in[16];
    const float* d2_ew = (const float*)d_in[17]; const float* d2_eb = (const float*)d_in[18];
    const float* d2_sw = (const float*)d_in[19]; const float* d2_sb = (const float*)d_in[20];
    const float* d2_bw = (const float*)d_in[21]; const float* d2_bb = (const float*)d_in[22];
    const float* sc_w  = (const float*)d_in[23]; const float* sc_b  = (const float*)d_in[24];
    const float* bi1_w = (const float*)d_in[25]; const float* bi1_b = (const float*)d_in[26];
    const float* bi2_w = (const float*)d_in[27]; const float* bi2_b = (const float*)d_in[28];

    char* ws = (char*)d_ws;
    size_t off = 0;
    ushort_t* wb = (ushort_t*)ws;              off += 1327360;
    float* stats = (float*)(ws + off);         off += 512;
    char* R1 = ws + off;                       off += 37748736;   // aux_bf -> mid32
    char* R2 = ws + off;                       off += 16777216;   // a_bf (a1 then a2)
    char* R3 = ws + off;                       off += 33554432;   // G32 (g1,g2,gamma3)
    char* R4 = ws + off;                       off += 50331648;   // q0/k0/v0 bf -> SP -> t32
    char* R5 = ws + off;                       off += 50331648;   // Qp/KT/Vp -> o32

    ushort_t* aux  = (ushort_t*)R1; float* mid32 = (float*)R1;
    ushort_t* abf  = (ushort_t*)R2;
    float*    G32  = (float*)R3;
    ushort_t* q0bf = (ushort_t*)R4; ushort_t* k0bf = q0bf + 8388608; ushort_t* v0bf = q0bf + 16777216;
    ushort_t* SP   = (ushort_t*)R4; float* t32 = (float*)R4;
    ushort_t* Qp   = (ushort_t*)R5; ushort_t* KT = Qp + 8388608; ushort_t* Vp = Qp + 16777216;
    float*    o32  = (float*)R5;

    ushort_t* wqw = wb,           *wkw = wb + 16384,  *wvw = wb + 32768;
    ushort_t* wew1 = wb + 49152,  *wsw1 = wb + 86016, *wbw1 = wb + 102400;
    ushort_t* wew2 = wb + 135168, *wsw2 = wb + 172032,*wbw2 = wb + 188416;
    ushort_t* wsct = wb + 221184, *wbi1 = wb + 368640,*wbi2 = wb + 516096;

    dim3 g(32, 16), blk(256);

    hipMemsetAsync(stats, 0, 512, stream);
    prep_w<<<2592, blk, 0, stream>>>(wb, q_w, k_w, v_w, d1_ew, d1_sw, d1_bw, d2_ew, d2_sw, d2_bw, sc_w, bi1_w, bi2_w);
    prep_aux<<<18432, blk, 0, stream>>>(aux, edge, seg, pe, ps);

    // phase 1: a1, g1, q0/k0/v0 (+LN stats), fused ADN -> patched Q/K/V
    gemm_conv<<<g, blk, 0, stream>>>(aux, 0, nullptr, 288, 9, wew1, d1_eb, 0, abf, 0, nullptr, nullptr, nullptr, stats, -1, -1);
    gemm_conv<<<g, blk, 0, stream>>>(abf, 0, nullptr, 128, 4, wsw1, d1_sb, 1, G32, 0, nullptr, nullptr, nullptr, stats, -1, -1);
    gemm_conv<<<g, blk, 0, stream>>>(x, 1, nullptr, 128, 4, wqw, q_b, 0, q0bf, 0, nullptr, nullptr, nullptr, stats, -1, 0);
    gemm_conv<<<g, blk, 0, stream>>>(x, 1, nullptr, 128, 4, wkw, k_b, 0, k0bf, 0, nullptr, nullptr, nullptr, stats, -1, 1);
    gemm_conv<<<g, blk, 0, stream>>>(x, 1, nullptr, 128, 4, wvw, v_b, 0, v0bf, 0, nullptr, nullptr, nullptr, stats, -1, 2);
    gemm_conv<<<g, blk, 0, stream>>>(q0bf, 0, abf, 256, 8, wbw1, d1_bb, 2, Qp, 1, q0bf, nullptr, G32, stats, 0, -1);
    gemm_conv<<<g, blk, 0, stream>>>(k0bf, 0, abf, 256, 8, wbw1, d1_bb, 2, KT, 2, k0bf, nullptr, G32, stats, 1, -1);
    gemm_conv<<<g, blk, 0, stream>>>(v0bf, 0, abf, 256, 8, wbw1, d1_bb, 2, Vp, 3, v0bf, nullptr, G32, stats, 2, -1);

    // a2/g2 before attention (frees aux region for mid32)
    gemm_conv<<<g, blk, 0, stream>>>(aux, 0, nullptr, 288, 9, wew2, d2_eb, 0, abf, 0, nullptr, nullptr, nullptr, stats, -1, -1);
    gemm_conv<<<g, blk, 0, stream>>>(abf, 0, nullptr, 128, 4, wsw2, d2_sb, 1, G32, 0, nullptr, nullptr, nullptr, stats, -1, -1);

    // attention: S = Q K^T (scaled), softmax, mid = x + P V (+mid LN stats)
    gemm_attn<<<dim3(8, 8, 16), blk, 0, stream>>>(Qp, 262144, 256, KT, 262144, 1024, 8, 0, 0.0625f, SP, 1048576, nullptr, nullptr, nullptr);
    gemm_attn<<<dim3(2, 2, 16), blk, 0, stream>>>(Qp + 4194304, 262144, 1024, KT + 4194304, 262144, 256, 32, 0, 0.03125f, SP + 16777216, 65536, nullptr, nullptr, nullptr);
    softmax_k<<<5120, blk, 0, stream>>>(SP);
    gemm_attn<<<dim3(2, 8, 16), blk, 0, stream>>>(SP, 1048576, 1024, Vp, 262144, 256, 32, 1, 1.f, nullptr, 0, x, mid32, stats);
    gemm_attn<<<dim3(8, 2, 16), blk, 0, stream>>>(SP + 16777216, 65536, 256, Vp + 4194304, 262144, 1024, 8, 2, 1.f, nullptr, 0, x, mid32, stats);

    // ADN2 -> o
    gemm_conv<<<g, blk, 0, stream>>>(mid32, 1, abf, 256, 8, wbw2, d2_bb, 3, o32, 0, nullptr, mid32, G32, stats, 3, -1);

    // conv3x3 tail
    conv3x3_mfma<1, 0><<<g, blk, 0, stream>>>(o32, wsct, sc_b, G32, nullptr, nullptr);
    conv3x3_mfma<2, 1><<<g, blk, 0, stream>>>(o32, wbi1, bi1_b, t32, nullptr, nullptr);
    conv3x3_mfma<1, 2><<<g, blk, 0, stream>>>(t32, wbi2, bi2_b, (float*)d_out, mid32, G32);
}

// Round 3
// 916.382 us; speedup vs baseline: 6.7903x; 1.1522x over previous
//
#include <hip/hip_runtime.h>
#include <cstdint>

typedef unsigned short ushort_t;
typedef unsigned int uint_t;
typedef __attribute__((ext_vector_type(8))) short short8;   // 8 bf16 (4 VGPRs) - MFMA A/B frag
typedef __attribute__((ext_vector_type(4))) float f32x4;    // MFMA C/D frag

#define MFMA16(a, b, c) __builtin_amdgcn_mfma_f32_16x16x32_bf16((a), (b), (c), 0, 0, 0)
// LDS chunk swizzle: logical 16B-chunk c of row r stored at phys chunk (c + r/4) & 3.
#define SWZ(c, r) ((((c) + ((r) >> 2)) & 3))
#define INV_N 1.9073486328125e-6f  // 1/524288

__device__ __forceinline__ ushort_t f2bf(float f) {
    uint_t u = __builtin_bit_cast(uint_t, f);
    u += 0x7FFFu + ((u >> 16) & 1u);          // RNE
    return (ushort_t)(u >> 16);
}
__device__ __forceinline__ float bf2f(ushort_t h) {
    return __builtin_bit_cast(float, (uint_t)h << 16);
}

// ===================== weight prep =====================
// wb offsets (elems): wqkv[384][128]=0, wew[256][288]=49152, wsw[256][128]=122880,
// wbw[256][256]=155648, wsct[9][128][128]=221184, wbi1=368640, wbi2=516096. tot 663552
__global__ __launch_bounds__(256) void prep_w(
    ushort_t* wb, const float* qw, const float* kw, const float* vw,
    const float* ew1, const float* ew2, const float* sw1, const float* sw2,
    const float* bw1, const float* bw2,
    const float* scw, const float* b1w, const float* b2w)
{
    int idx = blockIdx.x * 256 + threadIdx.x;
    if (idx >= 663552) return;
    float v;
    if (idx < 49152) {
        int z = idx >> 14, r = idx & 16383;
        v = (z == 0 ? qw : z == 1 ? kw : vw)[r];
    } else if (idx < 122880) {
        int j = idx - 49152; int z = j / 36864; int jj = j - z * 36864;
        int o = jj / 288, k = jj - o * 288;
        v = (k < 277) ? (z ? ew2 : ew1)[o * 277 + k] : 0.f;
    } else if (idx < 155648) {
        int j = idx - 122880; int z = j >> 14;
        v = (z ? sw2 : sw1)[j & 16383];
    } else if (idx < 221184) {
        int j = idx - 155648; int z = j >> 15;
        v = (z ? bw2 : bw1)[j & 32767];
    } else {
        int j = idx - 221184;
        const float* src = j < 147456 ? scw : j < 294912 ? b1w : b2w;
        j = j % 147456;
        int tap = j >> 14, r = (j >> 7) & 127, c = j & 127;
        v = src[r * 1152 + c * 9 + tap];
    }
    wb[idx] = f2bf(v);
}

// ===================== x transpose: f32 [b][128][4096] -> bf16 [b][4096][128] ==========
__global__ __launch_bounds__(256) void transp_x(const float* __restrict__ x, ushort_t* __restrict__ xT)
{
    __shared__ ushort_t tile[64 * 130];
    int b = blockIdx.y, p0 = blockIdx.x * 64;
    int t = threadIdx.x;
    for (int s = t; s < 8192; s += 256) {
        int c = s >> 6, p = s & 63;
        tile[p * 130 + c] = f2bf(x[((size_t)(b * 128 + c) << 12) + p0 + p]);
    }
    __syncthreads();
    for (int s = t; s < 8192; s += 256) {
        int p = s >> 7, c = s & 127;
        xT[((size_t)(b * 4096) + p0 + p) * 128 + c] = tile[p * 130 + c];
    }
}

// ===================== aux concat+transpose -> bf16 [b][4096][288] ==========
__global__ __launch_bounds__(256) void transp_aux(const float* __restrict__ edge, const float* __restrict__ seg,
                                                  const float* __restrict__ pe, const float* __restrict__ ps,
                                                  ushort_t* __restrict__ auxT)
{
    __shared__ ushort_t tile[64 * 292];
    int b = blockIdx.y, p0 = blockIdx.x * 64;
    int t = threadIdx.x;
    for (int s = t; s < 18432; s += 256) {
        int c = s >> 6, p = s & 63;
        float v = 0.f;
        if (c < 128)       v = edge[((size_t)(b * 128 + c) << 12) + p0 + p];
        else if (c < 256)  v = seg[((size_t)(b * 128 + c - 128) << 12) + p0 + p];
        else if (c == 256) v = pe[((size_t)b << 12) + p0 + p];
        else if (c < 277)  v = ps[((size_t)(b * 20 + c - 257) << 12) + p0 + p];
        tile[p * 292 + c] = f2bf(v);
    }
    __syncthreads();
    for (int s = t; s < 18432; s += 256) {
        int p = s / 288, c = s - p * 288;
        auxT[((size_t)(b * 4096) + p0 + p) * 288 + c] = tile[p * 292 + c];
    }
}

// ===================== conv1x1-family MFMA GEMM (B in [p][k] bf16) =====================
// grid (32 p-tiles, 16 b, Z). Out tile 128o x 128p. B: bA [b][4096][Kb1] (+z*zBoff), opt bB [b][4096][128].
// EP 0: bf16 out_z [b][p][128] (+stats slot z if dostats)
// EP 2: ADN1: v += (bA_tin - mu)*rstd*g; patch scatter to out_z (z==2 -> transposed)
// EP 3: ADN2: tin32 f32 [b][c][p]; out oT bf16 [b][p][128]
template <int EP>
__global__ __launch_bounds__(256) void gemm_conv(
    const ushort_t* bA, int Kb1, const ushort_t* bB, size_t zBoff,
    const ushort_t* wA, int wAperZ, int NK,
    const float* b0, const float* b1, const float* b2,
    ushort_t* o0, ushort_t* o1, ushort_t* o2,
    const ushort_t* gT, const float* tin32,
    float* stats, int dostats)
{
    __shared__ char lds[16448];
    int b = blockIdx.y, bx = blockIdx.x, z = blockIdx.z;
    int t = threadIdx.x, lane = t & 63, w = t >> 6;
    int wm = w & 1, wn = w >> 1, lo = lane & 15, quad = lane >> 4;
    int KtotA = Kb1 + (bB ? 128 : 0);
    const ushort_t* wAz = wA + (wAperZ ? (size_t)z * 128 * KtotA : 0);
    const ushort_t* bAz = bA + (size_t)z * zBoff;
    const float* bias = z == 0 ? b0 : z == 1 ? b1 : b2;
    ushort_t* outp = z == 0 ? o0 : z == 1 ? o1 : o2;

    f32x4 acc[4][4];
#pragma unroll
    for (int i = 0; i < 4; ++i)
#pragma unroll
        for (int j = 0; j < 4; ++j) acc[i][j] = (f32x4){0.f, 0.f, 0.f, 0.f};

    size_t prow = (size_t)(b * 4096 + bx * 128);
    for (int ck = 0; ck < NK; ++ck) {
        int k0 = ck * 32;
        __syncthreads();
#pragma unroll
        for (int s = t; s < 512; s += 256) {
            int r = s >> 2, c = s & 3;
            uint4 v = *(const uint4*)(wAz + (size_t)r * KtotA + k0 + c * 8);
            *(uint4*)(lds + r * 64 + SWZ(c, r) * 16) = v;
        }
#pragma unroll
        for (int s = t; s < 512; s += 256) {
            int r = s >> 2, c = s & 3;
            int kk = k0 + c * 8;
            const ushort_t* src = (kk < Kb1) ? bAz + (prow + r) * Kb1 + kk
                                             : bB + (prow + r) * 128 + (kk - Kb1);
            uint4 v = *(const uint4*)src;
            *(uint4*)(lds + 8192 + r * 64 + SWZ(c, r) * 16) = v;
        }
        __syncthreads();
        short8 af[4];
#pragma unroll
        for (int mt = 0; mt < 4; ++mt) {
            int row = wm * 64 + mt * 16 + lo;
            af[mt] = *(const short8*)(lds + row * 64 + SWZ(quad, row) * 16);
        }
#pragma unroll
        for (int nt = 0; nt < 4; ++nt) {
            int n = wn * 64 + nt * 16 + lo;
            short8 bf = *(const short8*)(lds + 8192 + n * 64 + SWZ(quad, n) * 16);
#pragma unroll
            for (int mt = 0; mt < 4; ++mt) acc[mt][nt] = MFMA16(af[mt], bf, acc[mt][nt]);
        }
    }

    float mean = 0.f, rstd = 0.f;
    if (EP == 2 || EP == 3) {
        int slot = (EP == 3) ? 3 : z;
        float s0 = stats[(slot * 16 + b) * 2], s1 = stats[(slot * 16 + b) * 2 + 1];
        mean = s0 * INV_N;
        rstd = rsqrtf(fmaxf(s1 * INV_N - mean * mean, 0.f) + 1e-5f);
    }
    float lsum = 0.f, lss = 0.f;
#pragma unroll
    for (int mt = 0; mt < 4; ++mt)
#pragma unroll
        for (int nt = 0; nt < 4; ++nt) {
            int oo0 = wm * 64 + mt * 16 + quad * 4;
            int pp = wn * 64 + nt * 16 + lo;
            int gp = bx * 128 + pp;
            size_t tbase = ((size_t)(b * 4096) + gp) * 128 + oo0;
            float vv[4];
#pragma unroll
            for (int r = 0; r < 4; ++r) vv[r] = acc[mt][nt][r] + bias[oo0 + r];
            if (EP == 0) {
                ushort4 st = {f2bf(vv[0]), f2bf(vv[1]), f2bf(vv[2]), f2bf(vv[3])};
                *(ushort4*)(outp + tbase) = st;
                if (dostats) {
#pragma unroll
                    for (int r = 0; r < 4; ++r) { lsum += vv[r]; lss += vv[r] * vv[r]; }
                }
            } else if (EP == 2) {
                ushort4 tv = *(const ushort4*)(bAz + tbase);
                ushort4 gv = *(const ushort4*)(gT + tbase);
                float tf[4] = {bf2f(tv.x), bf2f(tv.y), bf2f(tv.z), bf2f(tv.w)};
                float gf[4] = {bf2f(gv.x), bf2f(gv.y), bf2f(gv.z), bf2f(gv.w)};
                int y = gp >> 6, xx = gp & 63;
#pragma unroll
                for (int r = 0; r < 4; ++r) {
                    float v = vv[r] + (tf[r] - mean) * rstd * gf[r];
                    int oo = oo0 + r;
                    size_t idx;
                    if (oo < 64) {
                        int n = ((y >> 1) << 5) | (xx >> 1);
                        int f = (oo << 2) | ((y & 1) << 1) | (xx & 1);
                        idx = (z == 2) ? (((size_t)(b * 256 + f) << 10) + n)
                                       : (((size_t)(b * 1024 + n) << 8) + f);
                    } else {
                        int c = oo - 64;
                        int n = ((y >> 2) << 4) | (xx >> 2);
                        int f = (c << 4) | ((y & 3) << 2) | (xx & 3);
                        idx = 4194304u + ((z == 2) ? (((size_t)(b * 1024 + f) << 8) + n)
                                                   : (((size_t)(b * 256 + n) << 10) + f));
                    }
                    outp[idx] = f2bf(v);
                }
            } else {  // EP == 3
                ushort4 gv = *(const ushort4*)(gT + tbase);
                float gf[4] = {bf2f(gv.x), bf2f(gv.y), bf2f(gv.z), bf2f(gv.w)};
                ushort4 st;
#pragma unroll
                for (int r = 0; r < 4; ++r) {
                    int oo = oo0 + r;
                    float tf = tin32[((size_t)(b * 128 + oo) << 12) + gp];
                    float v = vv[r] + (tf - mean) * rstd * gf[r];
                    (&st.x)[r] = f2bf(v);
                }
                *(ushort4*)(outp + tbase) = st;
            }
        }
    if (EP == 0 && dostats) {
#pragma unroll
        for (int o2 = 32; o2 >= 1; o2 >>= 1) { lsum += __shfl_xor(lsum, o2); lss += __shfl_xor(lss, o2); }
        __syncthreads();
        float* red = (float*)lds;
        if (lane == 0) { red[w * 2] = lsum; red[w * 2 + 1] = lss; }
        __syncthreads();
        if (t == 0) {
            atomicAdd(&stats[(z * 16 + b) * 2], red[0] + red[2] + red[4] + red[6]);
            atomicAdd(&stats[(z * 16 + b) * 2 + 1], red[1] + red[3] + red[5] + red[7]);
        }
    }
}

// ===================== attention batched MFMA GEMM (A [row][k], B [col][k], both direct) =====
// EP 0: S*scale -> bf16 [rr][cc] ; EP 1: mid half0 scatter + stats ; EP 2: mid half1
__global__ __launch_bounds__(256) void gemm_attn(
    const ushort_t* A, size_t aBS, const ushort_t* Bm, size_t bBS,
    int Ka, int NK, int EP, float scale,
    ushort_t* sout, size_t soBS, int soNb,
    const float* x, float* mid32, ushort_t* midT, float* stats)
{
    __shared__ char lds[16448];
    int b = blockIdx.z, my = blockIdx.y, nx = blockIdx.x;
    int t = threadIdx.x, lane = t & 63, w = t >> 6;
    int wm = w & 1, wn = w >> 1, lo = lane & 15, quad = lane >> 4;

    f32x4 acc[4][4];
#pragma unroll
    for (int i = 0; i < 4; ++i)
#pragma unroll
        for (int j = 0; j < 4; ++j) acc[i][j] = (f32x4){0.f, 0.f, 0.f, 0.f};

    for (int ck = 0; ck < NK; ++ck) {
        int k0 = ck * 32;
        __syncthreads();
#pragma unroll
        for (int s = t; s < 512; s += 256) {
            int r = s >> 2, c = s & 3;
            uint4 v = *(const uint4*)(A + b * aBS + (size_t)(my * 128 + r) * Ka + k0 + c * 8);
            *(uint4*)(lds + r * 64 + SWZ(c, r) * 16) = v;
        }
#pragma unroll
        for (int s = t; s < 512; s += 256) {
            int r = s >> 2, c = s & 3;
            uint4 v = *(const uint4*)(Bm + b * bBS + (size_t)(nx * 128 + r) * Ka + k0 + c * 8);
            *(uint4*)(lds + 8192 + r * 64 + SWZ(c, r) * 16) = v;
        }
        __syncthreads();
        short8 af[4];
#pragma unroll
        for (int mt = 0; mt < 4; ++mt) {
            int row = wm * 64 + mt * 16 + lo;
            af[mt] = *(const short8*)(lds + row * 64 + SWZ(quad, row) * 16);
        }
#pragma unroll
        for (int nt = 0; nt < 4; ++nt) {
            int n = wn * 64 + nt * 16 + lo;
            short8 bf = *(const short8*)(lds + 8192 + n * 64 + SWZ(quad, n) * 16);
#pragma unroll
            for (int mt = 0; mt < 4; ++mt) acc[mt][nt] = MFMA16(af[mt], bf, acc[mt][nt]);
        }
    }

    float lsum = 0.f, lss = 0.f;
#pragma unroll
    for (int mt = 0; mt < 4; ++mt)
#pragma unroll
        for (int nt = 0; nt < 4; ++nt)
#pragma unroll
            for (int reg = 0; reg < 4; ++reg) {
                int rr = my * 128 + wm * 64 + mt * 16 + quad * 4 + reg;
                int cc = nx * 128 + wn * 64 + nt * 16 + lo;
                float v = acc[mt][nt][reg];
                if (EP == 0) {
                    sout[(size_t)b * soBS + (size_t)rr * soNb + cc] = f2bf(v * scale);
                } else {
                    int c, sp;
                    if (EP == 1) {
                        c = cc >> 2;
                        int py = (cc >> 1) & 1, px = cc & 1;
                        sp = (((rr >> 5) << 1) + py) * 64 + ((rr & 31) << 1) + px;
                    } else {
                        c = 64 + (cc >> 4);
                        int py = (cc >> 2) & 3, px = cc & 3;
                        sp = (((rr >> 4) << 2) + py) * 64 + ((rr & 15) << 2) + px;
                    }
                    size_t off = ((size_t)(b * 128 + c) << 12) + sp;
                    float vm = x[off] + v;
                    mid32[off] = vm;
                    midT[((size_t)(b * 4096) + sp) * 128 + c] = f2bf(vm);
                    lsum += vm; lss += vm * vm;
                }
            }
    if (EP >= 1) {
#pragma unroll
        for (int o2 = 32; o2 >= 1; o2 >>= 1) { lsum += __shfl_xor(lsum, o2); lss += __shfl_xor(lss, o2); }
        __syncthreads();
        float* red = (float*)lds;
        if (lane == 0) { red[w * 2] = lsum; red[w * 2 + 1] = lss; }
        __syncthreads();
        if (t == 0) {
            atomicAdd(&stats[(3 * 16 + b) * 2], red[0] + red[2] + red[4] + red[6]);
            atomicAdd(&stats[(3 * 16 + b) * 2 + 1], red[1] + red[3] + red[5] + red[7]);
        }
    }
}

// ===================== softmax (in-place bf16 S -> P) =====================
__global__ __launch_bounds__(256) void softmax_k(ushort_t* SP)
{
    int wid = blockIdx.x * 4 + (threadIdx.x >> 6);
    int lane = threadIdx.x & 63;
    ushort_t* row;
    int PL;
    if (wid < 16384) { row = SP + ((size_t)wid << 10); PL = 16; }
    else { int r2 = wid - 16384; row = SP + 16777216u + ((size_t)r2 << 8); PL = 4; }
    float v[16];
    float mx = -1e30f;
    for (int i = 0; i < PL; ++i) { v[i] = bf2f(row[lane + (i << 6)]); mx = fmaxf(mx, v[i]); }
#pragma unroll
    for (int o = 32; o >= 1; o >>= 1) mx = fmaxf(mx, __shfl_xor(mx, o));
    float sum = 0.f;
    for (int i = 0; i < PL; ++i) { v[i] = __expf(v[i] - mx); sum += v[i]; }
#pragma unroll
    for (int o = 32; o >= 1; o >>= 1) sum += __shfl_xor(sum, o);
    float inv = 1.f / sum;
    for (int i = 0; i < PL; ++i) row[lane + (i << 6)] = f2bf(v[i] * inv);
}

// ===================== conv3x3 implicit-GEMM MFMA (bf16 [p][c] input) =====================
// EP 0: tanh -> g3 f32 [b][p][128] ; EP 1: gelu -> tT bf16 [b][p][128] ; EP 2: mid*g3+acc+bias -> f32 [b][c][p]
template <int DIL, int EP>
__global__ __launch_bounds__(256) void conv3x3_mfma(
    const ushort_t* __restrict__ inT, const ushort_t* __restrict__ wt, const float* __restrict__ bias,
    void* __restrict__ out, const float* __restrict__ mid32, const float* __restrict__ g3T)
{
    constexpr int NR = 2 + 2 * DIL;
    __shared__ char lds[24576 + NR * 68 * 64];
    char* Braw = lds + 24576;
    int b = blockIdx.y;
    int y0 = blockIdx.x * 2;
    int t = threadIdx.x, lane = t & 63, w = t >> 6;
    int wm = w & 1, wn = w >> 1, lo = lane & 15, quad = lane >> 4;

    f32x4 acc[4][4];
#pragma unroll
    for (int i = 0; i < 4; ++i)
#pragma unroll
        for (int j = 0; j < 4; ++j) acc[i][j] = (f32x4){0.f, 0.f, 0.f, 0.f};

    for (int cc = 0; cc < 4; ++cc) {
        __syncthreads();
        constexpr int NSLOT = NR * 68 * 4;
        for (int s = t; s < NSLOT; s += 256) {
            int c4 = s & 3;
            int pr = s >> 2;            // rr*68 + xx
            int xx = pr % 68, rr = pr / 68;
            int ys = y0 - DIL + rr;
            int ix = xx - DIL;
            uint4 v = {0u, 0u, 0u, 0u};
            if (ys >= 0 && ys < 64 && (unsigned)ix < 64u)
                v = *(const uint4*)(inT + (size_t)(b * 4096 + ys * 64 + ix) * 128 + cc * 32 + c4 * 8);
            *(uint4*)(Braw + pr * 64 + SWZ(c4, pr) * 16) = v;
        }
        for (int ky = 0; ky < 3; ++ky) {
            __syncthreads();
            for (int s = t; s < 1536; s += 256) {
                int kx = s >> 9, r = (s >> 2) & 127, c = s & 3;
                uint4 v = *(const uint4*)(wt + ((size_t)((ky * 3 + kx) * 128 + r) << 7) + cc * 32 + c * 8);
                *(uint4*)(lds + kx * 8192 + r * 64 + SWZ(c, r) * 16) = v;
            }
            __syncthreads();
#pragma unroll
            for (int kx = 0; kx < 3; ++kx) {
                short8 af[4];
#pragma unroll
                for (int mt = 0; mt < 4; ++mt) {
                    int row = wm * 64 + mt * 16 + lo;
                    af[mt] = *(const short8*)(lds + kx * 8192 + row * 64 + SWZ(quad, row) * 16);
                }
#pragma unroll
                for (int nt = 0; nt < 4; ++nt) {
                    int n = wn * 64 + nt * 16 + lo;
                    int pr = ((n >> 6) + ky * DIL) * 68 + (n & 63) + kx * DIL;
                    short8 bf = *(const short8*)(Braw + pr * 64 + SWZ(quad, pr) * 16);
#pragma unroll
                    for (int mt = 0; mt < 4; ++mt) acc[mt][nt] = MFMA16(af[mt], bf, acc[mt][nt]);
                }
            }
        }
    }
#pragma unroll
    for (int mt = 0; mt < 4; ++mt)
#pragma unroll
        for (int nt = 0; nt < 4; ++nt) {
            int oo0 = wm * 64 + mt * 16 + quad * 4;
            int pp = wn * 64 + nt * 16 + lo;
            int sp = (y0 + (pp >> 6)) * 64 + (pp & 63);
            size_t tbase = ((size_t)(b * 4096) + sp) * 128 + oo0;
            if (EP == 0) {
                float4 st;
#pragma unroll
                for (int r = 0; r < 4; ++r)
                    (&st.x)[r] = tanhf(acc[mt][nt][r] + bias[oo0 + r]);
                *(float4*)((float*)out + tbase) = st;
            } else if (EP == 1) {
                ushort4 st;
#pragma unroll
                for (int r = 0; r < 4; ++r) {
                    float v = acc[mt][nt][r] + bias[oo0 + r];
                    (&st.x)[r] = f2bf(0.5f * v * (1.f + erff(v * 0.70710678118654752f)));
                }
                *(ushort4*)((ushort_t*)out + tbase) = st;
            } else {
                float4 gv = *(const float4*)(g3T + tbase);
#pragma unroll
                for (int r = 0; r < 4; ++r) {
                    int oo = oo0 + r;
                    size_t off = ((size_t)(b * 128 + oo) << 12) + sp;
                    ((float*)out)[off] = mid32[off] * (&gv.x)[r] + acc[mt][nt][r] + bias[oo];
                }
            }
        }
}

// ===================== launch =====================
extern "C" void kernel_launch(void* const* d_in, const int* in_sizes, int n_in,
                              void* d_out, int out_size, void* d_ws, size_t ws_size,
                              hipStream_t stream)
{
    const float* x    = (const float*)d_in[0];
    const float* edge = (const float*)d_in[1];
    const float* seg  = (const float*)d_in[2];
    const float* pe   = (const float*)d_in[3];
    const float* ps   = (const float*)d_in[4];
    const float* q_w  = (const float*)d_in[5];  const float* q_b  = (const float*)d_in[6];
    const float* k_w  = (const float*)d_in[7];  const float* k_b  = (const float*)d_in[8];
    const float* v_w  = (const float*)d_in[9];  const float* v_b  = (const float*)d_in[10];
    const float* d1_ew = (const float*)d_in[11]; const float* d1_eb = (const float*)d_in[12];
    const float* d1_sw = (const float*)d_in[13]; const float* d1_sb = (const float*)d_in[14];
    const float* d1_bw = (const float*)d_in[15]; const float* d1_bb = (const float*)d_in[16];
    const float* d2_ew = (const float*)d_in[17]; const float* d2_eb = (const float*)d_in[18];
    const float* d2_sw = (const float*)d_in[19]; const float* d2_sb = (const float*)d_in[20];
    const float* d2_bw = (const float*)d_in[21]; const float* d2_bb = (const float*)d_in[22];
    const float* sc_w  = (const float*)d_in[23]; const float* sc_b  = (const float*)d_in[24];
    const float* bi1_w = (const float*)d_in[25]; const float* bi1_b = (const float*)d_in[26];
    const float* bi2_w = (const float*)d_in[27]; const float* bi2_b = (const float*)d_in[28];

    char* ws = (char*)d_ws;
    ushort_t* wb = (ushort_t*)ws;                     // 1,327,360 B
    float* stats = (float*)(ws + 1327360);            // 512 B
    char* RA = ws + 1327872;                          // 37,748,736: auxT -> SP
    char* RB = RA + 37748736;                         // 16,777,216: xT -> midT
    char* RC = RB + 16777216;                         // 50,331,648: q0T/k0T/v0T -> mid32+oT
    char* RD = RC + 50331648;                         // 33,554,432: a1T,a2T
    char* RE = RD + 33554432;                         // 33,554,432: g1,g2
    char* RF = RE + 33554432;                         // 33,554,432: Qp,Kp -> g3
    char* RG = RF + 33554432;                         // 16,777,216: VT -> tT

    ushort_t* auxT = (ushort_t*)RA;
    ushort_t* SP0  = (ushort_t*)RA;
    ushort_t* xT   = (ushort_t*)RB;
    ushort_t* midT = (ushort_t*)RB;
    ushort_t* q0T  = (ushort_t*)RC;
    float*    mid32= (float*)RC;
    ushort_t* oT   = (ushort_t*)(RC + 33554432);
    ushort_t* a1T  = (ushort_t*)RD;
    ushort_t* g1   = (ushort_t*)RE;
    ushort_t* g2   = g1 + 8388608;
    ushort_t* Qp   = (ushort_t*)RF;
    ushort_t* Kp   = Qp + 8388608;
    float*    g3   = (float*)RF;
    ushort_t* VT   = (ushort_t*)RG;
    ushort_t* tT   = (ushort_t*)RG;
    const size_t ZB = 8388608;

    dim3 blk(256);

    hipMemsetAsync(stats, 0, 512, stream);
    prep_w<<<2592, blk, 0, stream>>>(wb, q_w, k_w, v_w, d1_ew, d2_ew, d1_sw, d2_sw, d1_bw, d2_bw, sc_w, bi1_w, bi2_w);
    transp_x<<<dim3(64, 16), blk, 0, stream>>>(x, xT);
    transp_aux<<<dim3(64, 16), blk, 0, stream>>>(edge, seg, pe, ps, auxT);

    // ew12 -> a1T, a2T
    gemm_conv<0><<<dim3(32, 16, 2), blk, 0, stream>>>(auxT, 288, nullptr, 0, wb + 49152, 1, 9,
        d1_eb, d2_eb, nullptr, a1T, a1T + ZB, nullptr, nullptr, nullptr, stats, 0);
    // sw12 -> g1, g2
    gemm_conv<0><<<dim3(32, 16, 2), blk, 0, stream>>>(a1T, 128, nullptr, ZB, wb + 122880, 1, 4,
        d1_sb, d2_sb, nullptr, g1, g2, nullptr, nullptr, nullptr, stats, 0);
    // qkv -> q0T,k0T,v0T (+stats 0,1,2)
    gemm_conv<0><<<dim3(32, 16, 3), blk, 0, stream>>>(xT, 128, nullptr, 0, wb, 1, 4,
        q_b, k_b, v_b, q0T, q0T + ZB, q0T + 2 * ZB, nullptr, nullptr, stats, 1);
    // adn1 -> Qp, Kp, VT (patch scatter)
    gemm_conv<2><<<dim3(32, 16, 3), blk, 0, stream>>>(q0T, 128, a1T, ZB, wb + 155648, 0, 8,
        d1_bb, d1_bb, d1_bb, Qp, Kp, VT, g1, nullptr, stats, 0);

    // attention
    gemm_attn<<<dim3(8, 8, 16), blk, 0, stream>>>(Qp, 262144, Kp, 262144, 256, 8, 0, 0.0625f,
        SP0, 1048576, 1024, nullptr, nullptr, nullptr, stats);
    gemm_attn<<<dim3(2, 2, 16), blk, 0, stream>>>(Qp + 4194304, 262144, Kp + 4194304, 262144, 1024, 32, 0, 0.03125f,
        SP0 + 16777216, 65536, 256, nullptr, nullptr, nullptr, stats);
    softmax_k<<<5120, blk, 0, stream>>>(SP0);
    gemm_attn<<<dim3(2, 8, 16), blk, 0, stream>>>(SP0, 1048576, VT, 262144, 1024, 32, 1, 1.f,
        nullptr, 0, 0, x, mid32, midT, stats);
    gemm_attn<<<dim3(8, 2, 16), blk, 0, stream>>>(SP0 + 16777216, 65536, VT + 4194304, 262144, 256, 8, 2, 1.f,
        nullptr, 0, 0, x, mid32, midT, stats);

    // adn2 -> oT
    gemm_conv<3><<<dim3(32, 16, 1), blk, 0, stream>>>(midT, 128, a1T + ZB, 0, wb + 155648 + 32768, 0, 8,
        d2_bb, nullptr, nullptr, oT, nullptr, nullptr, g2, mid32, stats, 0);

    // conv3x3 tail
    conv3x3_mfma<1, 0><<<dim3(32, 16), blk, 0, stream>>>(oT, wb + 221184, sc_b, g3, nullptr, nullptr);
    conv3x3_mfma<2, 1><<<dim3(32, 16), blk, 0, stream>>>(oT, wb + 368640, bi1_b, tT, nullptr, nullptr);
    conv3x3_mfma<1, 2><<<dim3(32, 16), blk, 0, stream>>>(tT, wb + 516096, bi2_b, d_out, mid32, g3);
}

// Round 4
// 710.279 us; speedup vs baseline: 8.7606x; 1.2902x over previous
//
#include <hip/hip_runtime.h>
#include <cstdint>

typedef unsigned short ushort_t;
typedef unsigned int uint_t;
typedef __attribute__((ext_vector_type(8))) short short8;   // 8 bf16 (4 VGPRs) - MFMA A/B frag
typedef __attribute__((ext_vector_type(4))) float f32x4;    // MFMA C/D frag

#define MFMA16(a, b, c) __builtin_amdgcn_mfma_f32_16x16x32_bf16((a), (b), (c), 0, 0, 0)
#define SWZ(c, r) ((((c) + ((r) >> 2)) & 3))
#define INV_N 1.9073486328125e-6f  // 1/524288

__device__ __forceinline__ ushort_t f2bf(float f) {
    uint_t u = __builtin_bit_cast(uint_t, f);
    u += 0x7FFFu + ((u >> 16) & 1u);          // RNE
    return (ushort_t)(u >> 16);
}
__device__ __forceinline__ float bf2f(ushort_t h) {
    return __builtin_bit_cast(float, (uint_t)h << 16);
}

// ===================== weight prep =====================
__global__ __launch_bounds__(256) void prep_w(
    ushort_t* wb, const float* qw, const float* kw, const float* vw,
    const float* ew1, const float* ew2, const float* sw1, const float* sw2,
    const float* bw1, const float* bw2,
    const float* scw, const float* b1w, const float* b2w)
{
    int idx = blockIdx.x * 256 + threadIdx.x;
    if (idx >= 663552) return;
    float v;
    if (idx < 49152) {
        int z = idx >> 14, r = idx & 16383;
        v = (z == 0 ? qw : z == 1 ? kw : vw)[r];
    } else if (idx < 122880) {
        int j = idx - 49152; int z = j / 36864; int jj = j - z * 36864;
        int o = jj / 288, k = jj - o * 288;
        v = (k < 277) ? (z ? ew2 : ew1)[o * 277 + k] : 0.f;
    } else if (idx < 155648) {
        int j = idx - 122880; int z = j >> 14;
        v = (z ? sw2 : sw1)[j & 16383];
    } else if (idx < 221184) {
        int j = idx - 155648; int z = j >> 15;
        v = (z ? bw2 : bw1)[j & 32767];
    } else {
        int j = idx - 221184;
        const float* src = j < 147456 ? scw : j < 294912 ? b1w : b2w;
        j = j % 147456;
        int tap = j >> 14, r = (j >> 7) & 127, c = j & 127;
        v = src[r * 1152 + c * 9 + tap];
    }
    wb[idx] = f2bf(v);
}

// ===================== x transpose: f32 [b][128][4096] -> bf16 [b][4096][128] ==========
__global__ __launch_bounds__(256) void transp_x(const float* __restrict__ x, ushort_t* __restrict__ xT)
{
    __shared__ ushort_t tile[64 * 130];
    int b = blockIdx.y, p0 = blockIdx.x * 64;
    int t = threadIdx.x;
    for (int s = t; s < 8192; s += 256) {
        int c = s >> 6, p = s & 63;
        tile[p * 130 + c] = f2bf(x[((size_t)(b * 128 + c) << 12) + p0 + p]);
    }
    __syncthreads();
    for (int s = t; s < 8192; s += 256) {
        int p = s >> 7, c = s & 127;
        xT[((size_t)(b * 4096) + p0 + p) * 128 + c] = tile[p * 130 + c];
    }
}

// ===================== aux concat+transpose -> bf16 [b][4096][288] ==========
__global__ __launch_bounds__(256) void transp_aux(const float* __restrict__ edge, const float* __restrict__ seg,
                                                  const float* __restrict__ pe, const float* __restrict__ ps,
                                                  ushort_t* __restrict__ auxT)
{
    __shared__ ushort_t tile[64 * 292];
    int b = blockIdx.y, p0 = blockIdx.x * 64;
    int t = threadIdx.x;
    for (int s = t; s < 18432; s += 256) {
        int c = s >> 6, p = s & 63;
        float v = 0.f;
        if (c < 128)       v = edge[((size_t)(b * 128 + c) << 12) + p0 + p];
        else if (c < 256)  v = seg[((size_t)(b * 128 + c - 128) << 12) + p0 + p];
        else if (c == 256) v = pe[((size_t)b << 12) + p0 + p];
        else if (c < 277)  v = ps[((size_t)(b * 20 + c - 257) << 12) + p0 + p];
        tile[p * 292 + c] = f2bf(v);
    }
    __syncthreads();
    for (int s = t; s < 18432; s += 256) {
        int p = s / 288, c = s - p * 288;
        auxT[((size_t)(b * 4096) + p0 + p) * 288 + c] = tile[p * 292 + c];
    }
}

// ===================== conv1x1-family MFMA GEMM (B in [p][k] bf16, reg-prefetch) ===========
// EP 0: bf16 out_z [b][p][128] (+stats slot z if dostats)
// EP 2: ADN1: v += (tin - mu)*rstd*g; coalesced patch scatter via LDS (z==2 -> transposed V)
// EP 3: ADN2: tin = bAz bf16; out [p][128] bf16
template <int EP>
__global__ __launch_bounds__(256) void gemm_conv(
    const ushort_t* bA, int Kb1, const ushort_t* bB, size_t zBoff,
    const ushort_t* wA, int wAperZ, int NK,
    const float* b0, const float* b1, const float* b2,
    ushort_t* o0, ushort_t* o1, ushort_t* o2,
    const ushort_t* gT, float* stats, int dostats)
{
    constexpr int LDSZ = (EP == 2) ? 33792 : 16448;
    __shared__ char lds[LDSZ];
    int b = blockIdx.y, bx = blockIdx.x, z = blockIdx.z;
    int t = threadIdx.x, lane = t & 63, w = t >> 6;
    int wm = w & 1, wn = w >> 1, lo = lane & 15, quad = lane >> 4;
    int KtotA = Kb1 + (bB ? 128 : 0);
    const ushort_t* wAz = wA + (wAperZ ? (size_t)z * 128 * KtotA : 0);
    const ushort_t* bAz = bA + (size_t)z * zBoff;
    const float* bias = z == 0 ? b0 : z == 1 ? b1 : b2;
    ushort_t* outp = z == 0 ? o0 : z == 1 ? o1 : o2;

    f32x4 acc[4][4];
#pragma unroll
    for (int i = 0; i < 4; ++i)
#pragma unroll
        for (int j = 0; j < 4; ++j) acc[i][j] = (f32x4){0.f, 0.f, 0.f, 0.f};

    size_t prow = (size_t)(b * 4096 + bx * 128);
    int r0 = t >> 2, c0 = t & 3, r1 = r0 + 64;
    uint4 pfA0, pfA1, pfB0, pfB1;
    {
        pfA0 = *(const uint4*)(wAz + (size_t)r0 * KtotA + c0 * 8);
        pfA1 = *(const uint4*)(wAz + (size_t)r1 * KtotA + c0 * 8);
        int kk = c0 * 8;
        const ushort_t* s0 = (kk < Kb1) ? bAz + (prow + r0) * Kb1 + kk : bB + (prow + r0) * 128 + (kk - Kb1);
        const ushort_t* s1 = (kk < Kb1) ? bAz + (prow + r1) * Kb1 + kk : bB + (prow + r1) * 128 + (kk - Kb1);
        pfB0 = *(const uint4*)s0;
        pfB1 = *(const uint4*)s1;
    }
    for (int ck = 0; ck < NK; ++ck) {
        __syncthreads();
        *(uint4*)(lds + r0 * 64 + SWZ(c0, r0) * 16) = pfA0;
        *(uint4*)(lds + r1 * 64 + SWZ(c0, r1) * 16) = pfA1;
        *(uint4*)(lds + 8192 + r0 * 64 + SWZ(c0, r0) * 16) = pfB0;
        *(uint4*)(lds + 8192 + r1 * 64 + SWZ(c0, r1) * 16) = pfB1;
        __syncthreads();
        if (ck + 1 < NK) {
            int k0 = (ck + 1) * 32;
            pfA0 = *(const uint4*)(wAz + (size_t)r0 * KtotA + k0 + c0 * 8);
            pfA1 = *(const uint4*)(wAz + (size_t)r1 * KtotA + k0 + c0 * 8);
            int kk = k0 + c0 * 8;
            const ushort_t* s0 = (kk < Kb1) ? bAz + (prow + r0) * Kb1 + kk : bB + (prow + r0) * 128 + (kk - Kb1);
            const ushort_t* s1 = (kk < Kb1) ? bAz + (prow + r1) * Kb1 + kk : bB + (prow + r1) * 128 + (kk - Kb1);
            pfB0 = *(const uint4*)s0;
            pfB1 = *(const uint4*)s1;
        }
        short8 af[4];
#pragma unroll
        for (int mt = 0; mt < 4; ++mt) {
            int row = wm * 64 + mt * 16 + lo;
            af[mt] = *(const short8*)(lds + row * 64 + SWZ(quad, row) * 16);
        }
#pragma unroll
        for (int nt = 0; nt < 4; ++nt) {
            int n = wn * 64 + nt * 16 + lo;
            short8 bf = *(const short8*)(lds + 8192 + n * 64 + SWZ(quad, n) * 16);
#pragma unroll
            for (int mt = 0; mt < 4; ++mt) acc[mt][nt] = MFMA16(af[mt], bf, acc[mt][nt]);
        }
    }

    float mean = 0.f, rstd = 0.f;
    if (EP >= 2) {
        int slot = (EP == 3) ? 3 : z;
        float s0 = stats[(slot * 16 + b) * 2], s1 = stats[(slot * 16 + b) * 2 + 1];
        mean = s0 * INV_N;
        rstd = rsqrtf(fmaxf(s1 * INV_N - mean * mean, 0.f) + 1e-5f);
    }
    float lsum = 0.f, lss = 0.f;
    if (EP == 2) {
        __syncthreads();   // LDS frag reads done; reuse as Cs
        ushort_t* Cs = (ushort_t*)lds;
#pragma unroll
        for (int mt = 0; mt < 4; ++mt)
#pragma unroll
            for (int nt = 0; nt < 4; ++nt) {
                int oo0 = wm * 64 + mt * 16 + quad * 4;
                int pp = wn * 64 + nt * 16 + lo;
                size_t tbase = (prow + pp) * 128 + oo0;
                ushort4 tv = *(const ushort4*)(bAz + tbase);
                ushort4 gv = *(const ushort4*)(gT + tbase);
#pragma unroll
                for (int r = 0; r < 4; ++r) {
                    float v = acc[mt][nt][r] + bias[oo0 + r]
                            + (bf2f((&tv.x)[r]) - mean) * rstd * bf2f((&gv.x)[r]);
                    Cs[(oo0 + r) * 132 + pp] = f2bf(v);
                }
            }
        __syncthreads();
        int y0 = bx * 2;
        if (z < 2) {
            // half0: [n][f] rows of 256, 16B stores
            for (int s = t; s < 1024; s += 256) {
                int n_l = s >> 5, fq = s & 31;
                ushort_t tmp[8];
#pragma unroll
                for (int e = 0; e < 8; ++e) {
                    int f = fq * 8 + e;
                    tmp[e] = Cs[(f >> 2) * 132 + ((f >> 1) & 1) * 64 + n_l * 2 + (f & 1)];
                }
                uint4 ov;
                ov.x = (uint_t)tmp[0] | ((uint_t)tmp[1] << 16);
                ov.y = (uint_t)tmp[2] | ((uint_t)tmp[3] << 16);
                ov.z = (uint_t)tmp[4] | ((uint_t)tmp[5] << 16);
                ov.w = (uint_t)tmp[6] | ((uint_t)tmp[7] << 16);
                *(uint4*)(outp + ((size_t)(b * 1024 + (y0 >> 1) * 32 + n_l) << 8) + fq * 8) = ov;
            }
            // half1: [n][f] rows of 1024, 8B stores
            int n0 = (y0 >> 2) << 4, py0 = y0 & 3;
            for (int s = t; s < 2048; s += 256) {
                int n_l = s & 15, c = (s >> 4) & 63, py = s >> 10;
                ushort_t tmp[4];
#pragma unroll
                for (int px = 0; px < 4; ++px)
                    tmp[px] = Cs[(64 + c) * 132 + py * 64 + n_l * 4 + px];
                uint2 ov;
                ov.x = (uint_t)tmp[0] | ((uint_t)tmp[1] << 16);
                ov.y = (uint_t)tmp[2] | ((uint_t)tmp[3] << 16);
                *(uint2*)(outp + 4194304u + ((size_t)(b * 256 + n0 + n_l) << 10) + c * 16 + (py0 + py) * 4) = ov;
            }
        } else {
            // VT half0: [f][m] rows of 1024
            int n0h0 = (y0 >> 1) * 32;
            for (int s = t; s < 2048; s += 256) {
                int f = s >> 3, j = s & 7;
                int oo = f >> 2, py = (f >> 1) & 1, px = f & 1;
                ushort_t tmp[4];
#pragma unroll
                for (int i2 = 0; i2 < 4; ++i2)
                    tmp[i2] = Cs[oo * 132 + py * 64 + (j * 4 + i2) * 2 + px];
                uint2 ov;
                ov.x = (uint_t)tmp[0] | ((uint_t)tmp[1] << 16);
                ov.y = (uint_t)tmp[2] | ((uint_t)tmp[3] << 16);
                *(uint2*)(outp + ((size_t)(b * 256 + f) << 10) + n0h0 + j * 4) = ov;
            }
            // VT half1: [f][m] rows of 256
            int n0 = (y0 >> 2) << 4, py0 = y0 & 3;
            for (int s = t; s < 2048; s += 256) {
                int fi = s >> 2, j = s & 3;
                int c = fi >> 3, py = (fi >> 2) & 1, px = fi & 3;
                int f = c * 16 + (py0 + py) * 4 + px;
                ushort_t tmp[4];
#pragma unroll
                for (int i2 = 0; i2 < 4; ++i2)
                    tmp[i2] = Cs[(64 + c) * 132 + py * 64 + (j * 4 + i2) * 4 + px];
                uint2 ov;
                ov.x = (uint_t)tmp[0] | ((uint_t)tmp[1] << 16);
                ov.y = (uint_t)tmp[2] | ((uint_t)tmp[3] << 16);
                *(uint2*)(outp + 4194304u + ((size_t)(b * 1024 + f) << 8) + n0 + j * 4) = ov;
            }
        }
    } else {
#pragma unroll
        for (int mt = 0; mt < 4; ++mt)
#pragma unroll
            for (int nt = 0; nt < 4; ++nt) {
                int oo0 = wm * 64 + mt * 16 + quad * 4;
                int pp = wn * 64 + nt * 16 + lo;
                size_t tbase = (prow + pp) * 128 + oo0;
                float vv[4];
#pragma unroll
                for (int r = 0; r < 4; ++r) vv[r] = acc[mt][nt][r] + bias[oo0 + r];
                if (EP == 3) {
                    ushort4 tv = *(const ushort4*)(bAz + tbase);
                    ushort4 gv = *(const ushort4*)(gT + tbase);
#pragma unroll
                    for (int r = 0; r < 4; ++r)
                        vv[r] += (bf2f((&tv.x)[r]) - mean) * rstd * bf2f((&gv.x)[r]);
                }
                ushort4 st = {f2bf(vv[0]), f2bf(vv[1]), f2bf(vv[2]), f2bf(vv[3])};
                *(ushort4*)(outp + tbase) = st;
                if (EP == 0 && dostats) {
#pragma unroll
                    for (int r = 0; r < 4; ++r) { lsum += vv[r]; lss += vv[r] * vv[r]; }
                }
            }
    }
    if (EP == 0 && dostats) {
#pragma unroll
        for (int o2 = 32; o2 >= 1; o2 >>= 1) { lsum += __shfl_xor(lsum, o2); lss += __shfl_xor(lss, o2); }
        __syncthreads();
        float* red = (float*)lds;
        if (lane == 0) { red[w * 2] = lsum; red[w * 2 + 1] = lss; }
        __syncthreads();
        if (t == 0) {
            atomicAdd(&stats[(z * 16 + b) * 2], red[0] + red[2] + red[4] + red[6]);
            atomicAdd(&stats[(z * 16 + b) * 2 + 1], red[1] + red[3] + red[5] + red[7]);
        }
    }
}

// ===================== attention batched MFMA GEMM (reg-prefetch) =====================
// EP 0: S*scale -> bf16 ; EP 1: mid half0 (bf16, via LDS coalesce, + stats) ; EP 2: mid half1
template <int EP>
__global__ __launch_bounds__(256) void gemm_attn(
    const ushort_t* A, size_t aBS, const ushort_t* Bm, size_t bBS,
    int Ka, int NK, float scale,
    ushort_t* sout, size_t soBS, int soNb,
    const ushort_t* xT, ushort_t* midT, float* stats)
{
    constexpr int LDSZ = (EP >= 1) ? 33792 : 16448;
    __shared__ char lds[LDSZ];
    int b = blockIdx.z, my = blockIdx.y, nx = blockIdx.x;
    int t = threadIdx.x, lane = t & 63, w = t >> 6;
    int wm = w & 1, wn = w >> 1, lo = lane & 15, quad = lane >> 4;

    f32x4 acc[4][4];
#pragma unroll
    for (int i = 0; i < 4; ++i)
#pragma unroll
        for (int j = 0; j < 4; ++j) acc[i][j] = (f32x4){0.f, 0.f, 0.f, 0.f};

    const ushort_t* Ab = A + b * aBS + (size_t)(my * 128) * Ka;
    const ushort_t* Bb = Bm + b * bBS + (size_t)(nx * 128) * Ka;
    int r0 = t >> 2, c0 = t & 3, r1 = r0 + 64;
    uint4 pfA0 = *(const uint4*)(Ab + (size_t)r0 * Ka + c0 * 8);
    uint4 pfA1 = *(const uint4*)(Ab + (size_t)r1 * Ka + c0 * 8);
    uint4 pfB0 = *(const uint4*)(Bb + (size_t)r0 * Ka + c0 * 8);
    uint4 pfB1 = *(const uint4*)(Bb + (size_t)r1 * Ka + c0 * 8);
    for (int ck = 0; ck < NK; ++ck) {
        __syncthreads();
        *(uint4*)(lds + r0 * 64 + SWZ(c0, r0) * 16) = pfA0;
        *(uint4*)(lds + r1 * 64 + SWZ(c0, r1) * 16) = pfA1;
        *(uint4*)(lds + 8192 + r0 * 64 + SWZ(c0, r0) * 16) = pfB0;
        *(uint4*)(lds + 8192 + r1 * 64 + SWZ(c0, r1) * 16) = pfB1;
        __syncthreads();
        if (ck + 1 < NK) {
            int k0 = (ck + 1) * 32;
            pfA0 = *(const uint4*)(Ab + (size_t)r0 * Ka + k0 + c0 * 8);
            pfA1 = *(const uint4*)(Ab + (size_t)r1 * Ka + k0 + c0 * 8);
            pfB0 = *(const uint4*)(Bb + (size_t)r0 * Ka + k0 + c0 * 8);
            pfB1 = *(const uint4*)(Bb + (size_t)r1 * Ka + k0 + c0 * 8);
        }
        short8 af[4];
#pragma unroll
        for (int mt = 0; mt < 4; ++mt) {
            int row = wm * 64 + mt * 16 + lo;
            af[mt] = *(const short8*)(lds + row * 64 + SWZ(quad, row) * 16);
        }
#pragma unroll
        for (int nt = 0; nt < 4; ++nt) {
            int n = wn * 64 + nt * 16 + lo;
            short8 bf = *(const short8*)(lds + 8192 + n * 64 + SWZ(quad, n) * 16);
#pragma unroll
            for (int mt = 0; mt < 4; ++mt) acc[mt][nt] = MFMA16(af[mt], bf, acc[mt][nt]);
        }
    }

    if (EP == 0) {
#pragma unroll
        for (int mt = 0; mt < 4; ++mt)
#pragma unroll
            for (int nt = 0; nt < 4; ++nt)
#pragma unroll
                for (int reg = 0; reg < 4; ++reg) {
                    int rr = my * 128 + wm * 64 + mt * 16 + quad * 4 + reg;
                    int cc = nx * 128 + wn * 64 + nt * 16 + lo;
                    sout[(size_t)b * soBS + (size_t)rr * soNb + cc] = f2bf(acc[mt][nt][reg] * scale);
                }
        return;
    }
    // EP 1/2: coalesced mid via LDS
    __syncthreads();
    ushort_t* Cs = (ushort_t*)lds;
#pragma unroll
    for (int mt = 0; mt < 4; ++mt)
#pragma unroll
        for (int nt = 0; nt < 4; ++nt)
#pragma unroll
            for (int reg = 0; reg < 4; ++reg) {
                int r_l = wm * 64 + mt * 16 + quad * 4 + reg;
                int c_l = wn * 64 + nt * 16 + lo;
                Cs[r_l * 132 + c_l] = f2bf(acc[mt][nt][reg]);
            }
    __syncthreads();
    float lsum = 0.f, lss = 0.f;
    for (int s = t; s < 4096; s += 256) {
        int sp, r_l, cbase, pybit, pxbit;
        if (EP == 1) {
            int sp_l = s >> 3, cj = s & 7;
            int y_l = sp_l >> 6, xv = sp_l & 63;
            r_l = (y_l >> 1) * 32 + (xv >> 1);
            sp = (my * 8 + y_l) * 64 + xv;
            cbase = nx * 32 + cj * 4;
            pybit = (y_l & 1) * 2 + (xv & 1);
            pxbit = 4;   // c_l stride per ci
        } else {
            int sp_l = s >> 1, cj = s & 1;
            int y_l = sp_l >> 6, xv = sp_l & 63;
            r_l = (y_l >> 2) * 16 + (xv >> 2);
            sp = (my * 32 + y_l) * 64 + xv;
            cbase = 64 + nx * 8 + cj * 4;
            pybit = (y_l & 3) * 4 + (xv & 3);
            pxbit = 16;
        }
        size_t base = ((size_t)(b * 4096) + sp) * 128 + cbase;
        ushort4 xv4 = *(const ushort4*)(xT + base);
        int c_l0 = (EP == 1) ? (cbase - nx * 32) * 4 + pybit : (cbase - 64 - nx * 8) * 16 + pybit;
        ushort_t o4[4];
#pragma unroll
        for (int ci = 0; ci < 4; ++ci) {
            float vm = bf2f(Cs[r_l * 132 + c_l0 + ci * pxbit]) + bf2f((&xv4.x)[ci]);
            o4[ci] = f2bf(vm);
            lsum += vm; lss += vm * vm;
        }
        ushort4 st = {o4[0], o4[1], o4[2], o4[3]};
        *(ushort4*)(midT + base) = st;
    }
#pragma unroll
    for (int o2 = 32; o2 >= 1; o2 >>= 1) { lsum += __shfl_xor(lsum, o2); lss += __shfl_xor(lss, o2); }
    __syncthreads();
    float* red = (float*)lds;
    if (lane == 0) { red[w * 2] = lsum; red[w * 2 + 1] = lss; }
    __syncthreads();
    if (t == 0) {
        atomicAdd(&stats[(3 * 16 + b) * 2], red[0] + red[2] + red[4] + red[6]);
        atomicAdd(&stats[(3 * 16 + b) * 2 + 1], red[1] + red[3] + red[5] + red[7]);
    }
}

// ===================== softmax (in-place bf16 S -> P) =====================
__global__ __launch_bounds__(256) void softmax_k(ushort_t* SP)
{
    int wid = blockIdx.x * 4 + (threadIdx.x >> 6);
    int lane = threadIdx.x & 63;
    ushort_t* row;
    int PL;
    if (wid < 16384) { row = SP + ((size_t)wid << 10); PL = 16; }
    else { int r2 = wid - 16384; row = SP + 16777216u + ((size_t)r2 << 8); PL = 4; }
    float v[16];
    float mx = -1e30f;
    for (int i = 0; i < PL; ++i) { v[i] = bf2f(row[lane + (i << 6)]); mx = fmaxf(mx, v[i]); }
#pragma unroll
    for (int o = 32; o >= 1; o >>= 1) mx = fmaxf(mx, __shfl_xor(mx, o));
    float sum = 0.f;
    for (int i = 0; i < PL; ++i) { v[i] = __expf(v[i] - mx); sum += v[i]; }
#pragma unroll
    for (int o = 32; o >= 1; o >>= 1) sum += __shfl_xor(sum, o);
    float inv = 1.f / sum;
    for (int i = 0; i < PL; ++i) row[lane + (i << 6)] = f2bf(v[i] * inv);
}

// ===================== conv3x3 implicit-GEMM MFMA (bf16 [p][c] input) =====================
// EP 0: tanh -> bf16 [p][128] ; EP 1: gelu -> bf16 [p][128] ; EP 2: midT*g3T + acc+bias -> f32 [c][p]
template <int DIL, int EP>
__global__ __launch_bounds__(256) void conv3x3_mfma(
    const ushort_t* __restrict__ inT, const ushort_t* __restrict__ wt, const float* __restrict__ bias,
    void* __restrict__ out, const ushort_t* __restrict__ midT, const ushort_t* __restrict__ g3T)
{
    constexpr int NR = 2 + 2 * DIL;
    __shared__ char lds[24576 + NR * 68 * 64];
    char* Braw = lds + 24576;
    int b = blockIdx.y;
    int y0 = blockIdx.x * 2;
    int t = threadIdx.x, lane = t & 63, w = t >> 6;
    int wm = w & 1, wn = w >> 1, lo = lane & 15, quad = lane >> 4;

    f32x4 acc[4][4];
#pragma unroll
    for (int i = 0; i < 4; ++i)
#pragma unroll
        for (int j = 0; j < 4; ++j) acc[i][j] = (f32x4){0.f, 0.f, 0.f, 0.f};

    for (int cc = 0; cc < 4; ++cc) {
        __syncthreads();
        constexpr int NSLOT = NR * 68 * 4;
        for (int s = t; s < NSLOT; s += 256) {
            int c4 = s & 3;
            int pr = s >> 2;
            int xx = pr % 68, rr = pr / 68;
            int ys = y0 - DIL + rr;
            int ix = xx - DIL;
            uint4 v = {0u, 0u, 0u, 0u};
            if (ys >= 0 && ys < 64 && (unsigned)ix < 64u)
                v = *(const uint4*)(inT + (size_t)(b * 4096 + ys * 64 + ix) * 128 + cc * 32 + c4 * 8);
            *(uint4*)(Braw + pr * 64 + SWZ(c4, pr) * 16) = v;
        }
        for (int ky = 0; ky < 3; ++ky) {
            __syncthreads();
            for (int s = t; s < 1536; s += 256) {
                int kx = s >> 9, r = (s >> 2) & 127, c = s & 3;
                uint4 v = *(const uint4*)(wt + ((size_t)((ky * 3 + kx) * 128 + r) << 7) + cc * 32 + c * 8);
                *(uint4*)(lds + kx * 8192 + r * 64 + SWZ(c, r) * 16) = v;
            }
            __syncthreads();
#pragma unroll
            for (int kx = 0; kx < 3; ++kx) {
                short8 af[4];
#pragma unroll
                for (int mt = 0; mt < 4; ++mt) {
                    int row = wm * 64 + mt * 16 + lo;
                    af[mt] = *(const short8*)(lds + kx * 8192 + row * 64 + SWZ(quad, row) * 16);
                }
#pragma unroll
                for (int nt = 0; nt < 4; ++nt) {
                    int n = wn * 64 + nt * 16 + lo;
                    int pr = ((n >> 6) + ky * DIL) * 68 + (n & 63) + kx * DIL;
                    short8 bf = *(const short8*)(Braw + pr * 64 + SWZ(quad, pr) * 16);
#pragma unroll
                    for (int mt = 0; mt < 4; ++mt) acc[mt][nt] = MFMA16(af[mt], bf, acc[mt][nt]);
                }
            }
        }
    }
#pragma unroll
    for (int mt = 0; mt < 4; ++mt)
#pragma unroll
        for (int nt = 0; nt < 4; ++nt) {
            int oo0 = wm * 64 + mt * 16 + quad * 4;
            int pp = wn * 64 + nt * 16 + lo;
            int sp = (y0 + (pp >> 6)) * 64 + (pp & 63);
            size_t tbase = ((size_t)(b * 4096) + sp) * 128 + oo0;
            if (EP == 0) {
                ushort4 st;
#pragma unroll
                for (int r = 0; r < 4; ++r)
                    (&st.x)[r] = f2bf(tanhf(acc[mt][nt][r] + bias[oo0 + r]));
                *(ushort4*)((ushort_t*)out + tbase) = st;
            } else if (EP == 1) {
                ushort4 st;
#pragma unroll
                for (int r = 0; r < 4; ++r) {
                    float v = acc[mt][nt][r] + bias[oo0 + r];
                    (&st.x)[r] = f2bf(0.5f * v * (1.f + erff(v * 0.70710678118654752f)));
                }
                *(ushort4*)((ushort_t*)out + tbase) = st;
            } else {
                ushort4 mv = *(const ushort4*)(midT + tbase);
                ushort4 gv = *(const ushort4*)(g3T + tbase);
#pragma unroll
                for (int r = 0; r < 4; ++r) {
                    int oo = oo0 + r;
                    size_t off = ((size_t)(b * 128 + oo) << 12) + sp;
                    ((float*)out)[off] = bf2f((&mv.x)[r]) * bf2f((&gv.x)[r]) + acc[mt][nt][r] + bias[oo];
                }
            }
        }
}

// ===================== launch =====================
extern "C" void kernel_launch(void* const* d_in, const int* in_sizes, int n_in,
                              void* d_out, int out_size, void* d_ws, size_t ws_size,
                              hipStream_t stream)
{
    const float* x    = (const float*)d_in[0];
    const float* edge = (const float*)d_in[1];
    const float* seg  = (const float*)d_in[2];
    const float* pe   = (const float*)d_in[3];
    const float* ps   = (const float*)d_in[4];
    const float* q_w  = (const float*)d_in[5];  const float* q_b  = (const float*)d_in[6];
    const float* k_w  = (const float*)d_in[7];  const float* k_b  = (const float*)d_in[8];
    const float* v_w  = (const float*)d_in[9];  const float* v_b  = (const float*)d_in[10];
    const float* d1_ew = (const float*)d_in[11]; const float* d1_eb = (const float*)d_in[12];
    const float* d1_sw = (const float*)d_in[13]; const float* d1_sb = (const float*)d_in[14];
    const float* d1_bw = (const float*)d_in[15]; const float* d1_bb = (const float*)d_in[16];
    const float* d2_ew = (const float*)d_in[17]; const float* d2_eb = (const float*)d_in[18];
    const float* d2_sw = (const float*)d_in[19]; const float* d2_sb = (const float*)d_in[20];
    const float* d2_bw = (const float*)d_in[21]; const float* d2_bb = (const float*)d_in[22];
    const float* sc_w  = (const float*)d_in[23]; const float* sc_b  = (const float*)d_in[24];
    const float* bi1_w = (const float*)d_in[25]; const float* bi1_b = (const float*)d_in[26];
    const float* bi2_w = (const float*)d_in[27]; const float* bi2_b = (const float*)d_in[28];

    char* ws = (char*)d_ws;
    ushort_t* wb = (ushort_t*)ws;                     // 1,327,360 B
    float* stats = (float*)(ws + 1327360);            // 512 B
    char* RA = ws + 1327872;                          // 37,748,736: auxT -> SP
    char* RB = RA + 37748736;                         // 16,777,216: xT (persists)
    char* RC = RB + 16777216;                         // 50,331,648: q0T/k0T/v0T -> midT + oT
    char* RD = RC + 50331648;                         // 33,554,432: a1T, a2T
    char* RE = RD + 33554432;                         // 33,554,432: g1, g2
    char* RF = RE + 33554432;                         // 33,554,432: Qp, Kp -> g3 (bf16)
    char* RG = RF + 33554432;                         // 16,777,216: VT -> tT

    ushort_t* auxT = (ushort_t*)RA;
    ushort_t* SP0  = (ushort_t*)RA;
    ushort_t* xT   = (ushort_t*)RB;
    ushort_t* q0T  = (ushort_t*)RC;
    ushort_t* midT = (ushort_t*)RC;
    ushort_t* oT   = (ushort_t*)(RC + 16777216);
    ushort_t* a1T  = (ushort_t*)RD;
    ushort_t* g1   = (ushort_t*)RE;
    ushort_t* g2   = g1 + 8388608;
    ushort_t* Qp   = (ushort_t*)RF;
    ushort_t* Kp   = Qp + 8388608;
    ushort_t* g3   = (ushort_t*)RF;
    ushort_t* VT   = (ushort_t*)RG;
    ushort_t* tT   = (ushort_t*)RG;
    const size_t ZB = 8388608;

    dim3 blk(256);

    hipMemsetAsync(stats, 0, 512, stream);
    prep_w<<<2592, blk, 0, stream>>>(wb, q_w, k_w, v_w, d1_ew, d2_ew, d1_sw, d2_sw, d1_bw, d2_bw, sc_w, bi1_w, bi2_w);
    transp_x<<<dim3(64, 16), blk, 0, stream>>>(x, xT);
    transp_aux<<<dim3(64, 16), blk, 0, stream>>>(edge, seg, pe, ps, auxT);

    // ew12 -> a1T, a2T
    gemm_conv<0><<<dim3(32, 16, 2), blk, 0, stream>>>(auxT, 288, nullptr, 0, wb + 49152, 1, 9,
        d1_eb, d2_eb, nullptr, a1T, a1T + ZB, nullptr, nullptr, stats, 0);
    // sw12 -> g1, g2
    gemm_conv<0><<<dim3(32, 16, 2), blk, 0, stream>>>(a1T, 128, nullptr, ZB, wb + 122880, 1, 4,
        d1_sb, d2_sb, nullptr, g1, g2, nullptr, nullptr, stats, 0);
    // qkv -> q0T,k0T,v0T (+stats 0,1,2)
    gemm_conv<0><<<dim3(32, 16, 3), blk, 0, stream>>>(xT, 128, nullptr, 0, wb, 1, 4,
        q_b, k_b, v_b, q0T, q0T + ZB, q0T + 2 * ZB, nullptr, stats, 1);
    // adn1 -> Qp, Kp, VT (coalesced patch scatter)
    gemm_conv<2><<<dim3(32, 16, 3), blk, 0, stream>>>(q0T, 128, a1T, ZB, wb + 155648, 0, 8,
        d1_bb, d1_bb, d1_bb, Qp, Kp, VT, g1, stats, 0);

    // attention
    gemm_attn<0><<<dim3(8, 8, 16), blk, 0, stream>>>(Qp, 262144, Kp, 262144, 256, 8, 0.0625f,
        SP0, 1048576, 1024, nullptr, nullptr, stats);
    gemm_attn<0><<<dim3(2, 2, 16), blk, 0, stream>>>(Qp + 4194304, 262144, Kp + 4194304, 262144, 1024, 32, 0.03125f,
        SP0 + 16777216, 65536, 256, nullptr, nullptr, stats);
    softmax_k<<<5120, blk, 0, stream>>>(SP0);
    gemm_attn<1><<<dim3(2, 8, 16), blk, 0, stream>>>(SP0, 1048576, VT, 262144, 1024, 32, 1.f,
        nullptr, 0, 0, xT, midT, stats);
    gemm_attn<2><<<dim3(8, 2, 16), blk, 0, stream>>>(SP0 + 16777216, 65536, VT + 4194304, 262144, 256, 8, 1.f,
        nullptr, 0, 0, xT, midT, stats);

    // adn2 -> oT (tin = midT)
    gemm_conv<3><<<dim3(32, 16, 1), blk, 0, stream>>>(midT, 128, a1T + ZB, 0, wb + 155648 + 32768, 0, 8,
        d2_bb, nullptr, nullptr, oT, nullptr, nullptr, g2, stats, 0);

    // conv3x3 tail
    conv3x3_mfma<1, 0><<<dim3(32, 16), blk, 0, stream>>>(oT, wb + 221184, sc_b, g3, nullptr, nullptr);
    conv3x3_mfma<2, 1><<<dim3(32, 16), blk, 0, stream>>>(oT, wb + 368640, bi1_b, tT, nullptr, nullptr);
    conv3x3_mfma<1, 2><<<dim3(32, 16), blk, 0, stream>>>(tT, wb + 516096, bi2_b, d_out, midT, g3);
}

// Round 5
// 702.122 us; speedup vs baseline: 8.8624x; 1.0116x over previous
//
#include <hip/hip_runtime.h>
#include <cstdint>

typedef unsigned short ushort_t;
typedef unsigned int uint_t;
typedef __attribute__((ext_vector_type(8))) short short8;   // 8 bf16 (4 VGPRs) - MFMA A/B frag
typedef __attribute__((ext_vector_type(4))) float f32x4;    // MFMA C/D frag

#define MFMA16(a, b, c) __builtin_amdgcn_mfma_f32_16x16x32_bf16((a), (b), (c), 0, 0, 0)
#define SWZ(c, r) ((((c) + ((r) >> 2)) & 3))
#define INV_N 1.9073486328125e-6f  // 1/524288

struct P4 { ushort_t* p[4]; };
struct B4 { const float* b[4]; };

__device__ __forceinline__ ushort_t f2bf(float f) {
    uint_t u = __builtin_bit_cast(uint_t, f);
    u += 0x7FFFu + ((u >> 16) & 1u);          // RNE
    return (ushort_t)(u >> 16);
}
__device__ __forceinline__ float bf2f(ushort_t h) {
    return __builtin_bit_cast(float, (uint_t)h << 16);
}

// ===================== weight prep (same layout as round 4) =====================
// wb elems: wqkv[384][128]=0, wew[256][288]=49152, wsw[256][128]=122880,
// wbw[256][256]=155648, wsct[9][128][128]=221184, wbi1=368640, wbi2=516096
__global__ __launch_bounds__(256) void prep_w(
    ushort_t* wb, const float* qw, const float* kw, const float* vw,
    const float* ew1, const float* ew2, const float* sw1, const float* sw2,
    const float* bw1, const float* bw2,
    const float* scw, const float* b1w, const float* b2w)
{
    int idx = blockIdx.x * 256 + threadIdx.x;
    if (idx >= 663552) return;
    float v;
    if (idx < 49152) {
        int z = idx >> 14, r = idx & 16383;
        v = (z == 0 ? qw : z == 1 ? kw : vw)[r];
    } else if (idx < 122880) {
        int j = idx - 49152; int z = j / 36864; int jj = j - z * 36864;
        int o = jj / 288, k = jj - o * 288;
        v = (k < 277) ? (z ? ew2 : ew1)[o * 277 + k] : 0.f;
    } else if (idx < 155648) {
        int j = idx - 122880; int z = j >> 14;
        v = (z ? sw2 : sw1)[j & 16383];
    } else if (idx < 221184) {
        int j = idx - 155648; int z = j >> 15;
        v = (z ? bw2 : bw1)[j & 32767];
    } else {
        int j = idx - 221184;
        const float* src = j < 147456 ? scw : j < 294912 ? b1w : b2w;
        j = j % 147456;
        int tap = j >> 14, r = (j >> 7) & 127, c = j & 127;
        v = src[r * 1152 + c * 9 + tap];
    }
    wb[idx] = f2bf(v);
}

// ===================== combined aux weights: wc[z][128][288] =====================
// z0: sw1@ew1 ; z1: bw1[:,128:]@ew1 ; z2: sw2@ew2 ; z3: bw2[:,128:]@ew2
__global__ __launch_bounds__(256) void combine_w(ushort_t* wc, const ushort_t* wb)
{
    __shared__ float ews[128 * 33];
    __shared__ ushort_t Ws[128 * 130];
    int z = blockIdx.y, nt = blockIdx.x, n0 = nt * 32;
    int t = threadIdx.x;
    const ushort_t* wew = wb + 49152;
    const ushort_t* wsw = wb + 122880;
    const ushort_t* wbw = wb + 155648;
    const ushort_t* W; int wstr, wof;
    if (z == 0)      { W = wsw;         wstr = 128; wof = 0; }
    else if (z == 1) { W = wbw;         wstr = 256; wof = 128; }
    else if (z == 2) { W = wsw + 16384; wstr = 128; wof = 0; }
    else             { W = wbw + 32768; wstr = 256; wof = 128; }
    const ushort_t* E = wew + (z >= 2 ? 36864 : 0);
    for (int s = t; s < 16384; s += 256) {
        int c = s & 127, o = s >> 7;
        Ws[c * 130 + o] = W[o * wstr + wof + c];
    }
    for (int s = t; s < 4096; s += 256) {
        int c = s >> 5, n = s & 31;
        ews[c * 33 + n] = bf2f(E[c * 288 + n0 + n]);
    }
    __syncthreads();
    int o = t & 127, nh = t >> 7;
    float acc[16];
#pragma unroll
    for (int i = 0; i < 16; ++i) acc[i] = 0.f;
    for (int c = 0; c < 128; ++c) {
        float wv = bf2f(Ws[c * 130 + o]);
#pragma unroll
        for (int i = 0; i < 16; ++i) acc[i] += wv * ews[c * 33 + nh * 16 + i];
    }
#pragma unroll
    for (int i = 0; i < 16; ++i)
        wc[(size_t)(z * 128 + o) * 288 + n0 + nh * 16 + i] = f2bf(acc[i]);
}

// combined biases bc[z][128] (fp32, from original fp32 params)
__global__ __launch_bounds__(512) void combine_bias(
    float* bc, const float* sw1, const float* bw1, const float* sw2, const float* bw2,
    const float* eb1, const float* eb2, const float* sb1, const float* bb1,
    const float* sb2, const float* bb2)
{
    int t = threadIdx.x; int z = t >> 7, o = t & 127;
    const float* W; int wstr, wof; const float* eb; float add;
    if (z == 0)      { W = sw1; wstr = 128; wof = 0;   eb = eb1; add = sb1[o]; }
    else if (z == 1) { W = bw1; wstr = 256; wof = 128; eb = eb1; add = bb1[o]; }
    else if (z == 2) { W = sw2; wstr = 128; wof = 0;   eb = eb2; add = sb2[o]; }
    else             { W = bw2; wstr = 256; wof = 128; eb = eb2; add = bb2[o]; }
    float s = add;
    for (int c = 0; c < 128; ++c) s += W[o * wstr + wof + c] * eb[c];
    bc[t] = s;
}

// ===================== x transpose: f32 [b][128][4096] -> bf16 [b][4096][128] (vectorized) ==
__global__ __launch_bounds__(256) void transp_x(const float* __restrict__ x, ushort_t* __restrict__ xT)
{
    __shared__ ushort_t tile[64 * 130];
    int b = blockIdx.y, p0 = blockIdx.x * 64;
    int t = threadIdx.x;
#pragma unroll
    for (int i = 0; i < 8; ++i) {
        int s = t + i * 256;
        int c = s >> 4, p4 = (s & 15) * 4;
        float4 f = *(const float4*)(x + ((size_t)(b * 128 + c) << 12) + p0 + p4);
        tile[(p4 + 0) * 130 + c] = f2bf(f.x);
        tile[(p4 + 1) * 130 + c] = f2bf(f.y);
        tile[(p4 + 2) * 130 + c] = f2bf(f.z);
        tile[(p4 + 3) * 130 + c] = f2bf(f.w);
    }
    __syncthreads();
#pragma unroll
    for (int i = 0; i < 4; ++i) {
        int s = t + i * 256;
        int p = s >> 4, c8 = (s & 15) * 8;
        ushort_t v[8];
#pragma unroll
        for (int e = 0; e < 8; ++e) v[e] = tile[p * 130 + c8 + e];
        uint4 ov = {(uint_t)v[0] | ((uint_t)v[1] << 16), (uint_t)v[2] | ((uint_t)v[3] << 16),
                    (uint_t)v[4] | ((uint_t)v[5] << 16), (uint_t)v[6] | ((uint_t)v[7] << 16)};
        *(uint4*)(xT + ((size_t)(b * 4096) + p0 + p) * 128 + c8) = ov;
    }
}

// ===================== aux concat+transpose -> bf16 [b][4096][288] (vectorized) ==========
__global__ __launch_bounds__(256) void transp_aux(const float* __restrict__ edge, const float* __restrict__ seg,
                                                  const float* __restrict__ pe, const float* __restrict__ ps,
                                                  ushort_t* __restrict__ auxT)
{
    __shared__ ushort_t tile[64 * 292];
    int b = blockIdx.y, p0 = blockIdx.x * 64;
    int t = threadIdx.x;
#pragma unroll
    for (int i = 0; i < 18; ++i) {
        int s = t + i * 256;
        int c = s >> 4, p4 = (s & 15) * 4;
        float4 f = {0.f, 0.f, 0.f, 0.f};
        if (c < 128)       f = *(const float4*)(edge + ((size_t)(b * 128 + c) << 12) + p0 + p4);
        else if (c < 256)  f = *(const float4*)(seg + ((size_t)(b * 128 + c - 128) << 12) + p0 + p4);
        else if (c == 256) f = *(const float4*)(pe + ((size_t)b << 12) + p0 + p4);
        else if (c < 277)  f = *(const float4*)(ps + ((size_t)(b * 20 + c - 257) << 12) + p0 + p4);
        tile[(p4 + 0) * 292 + c] = f2bf(f.x);
        tile[(p4 + 1) * 292 + c] = f2bf(f.y);
        tile[(p4 + 2) * 292 + c] = f2bf(f.z);
        tile[(p4 + 3) * 292 + c] = f2bf(f.w);
    }
    __syncthreads();
#pragma unroll
    for (int i = 0; i < 9; ++i) {
        int s = t + i * 256;
        int p = s / 36, c8 = (s % 36) * 8;
        ushort_t v[8];
#pragma unroll
        for (int e = 0; e < 8; ++e) v[e] = tile[p * 292 + c8 + e];
        uint4 ov = {(uint_t)v[0] | ((uint_t)v[1] << 16), (uint_t)v[2] | ((uint_t)v[3] << 16),
                    (uint_t)v[4] | ((uint_t)v[5] << 16), (uint_t)v[6] | ((uint_t)v[7] << 16)};
        *(uint4*)(auxT + ((size_t)(b * 4096) + p0 + p) * 288 + c8) = ov;
    }
}

// ===================== conv1x1-family MFMA GEMM =====================
// EP 0: v=acc+bias -> bf16 [b][p][128] (+stats slot z if dostats)
// EP 2: ADN1: v=acc + betT + (tin-mu)*rstd*gT; 4rowx32col tile, coalesced patch scatter
// EP 3: ADN2: same math, plain [p][128] out
template <int EP>
__global__ __launch_bounds__(256) void gemm_conv(
    const ushort_t* bA, int Kb1, size_t zBoff,
    const ushort_t* wA, int wstride, int wAperZ, int NK,
    B4 bias4, P4 out4, const ushort_t* gT, const ushort_t* betT,
    float* stats, int dostats)
{
    constexpr int LDSZ = (EP == 2) ? 33792 : 16448;
    __shared__ char lds[LDSZ];
    int b = blockIdx.y, bx = blockIdx.x, z = blockIdx.z;
    int t = threadIdx.x, lane = t & 63, w = t >> 6;
    int wm = w & 1, wn = w >> 1, lo = lane & 15, quad = lane >> 4;
    const ushort_t* wAz = wA + (wAperZ ? (size_t)z * 128 * wstride : 0);
    const ushort_t* bAz = bA + (size_t)z * zBoff;
    ushort_t* outp = out4.p[z];
    size_t bbase = (size_t)b * 4096;
    int y0 = 0, x0 = 0;
    if (EP == 2) { y0 = (bx >> 1) * 4; x0 = (bx & 1) * 32; }

    f32x4 acc[4][4];
#pragma unroll
    for (int i = 0; i < 4; ++i)
#pragma unroll
        for (int j = 0; j < 4; ++j) acc[i][j] = (f32x4){0.f, 0.f, 0.f, 0.f};

    int r0 = t >> 2, c0 = t & 3, r1 = r0 + 64;
    int gp0, gp1;
    if (EP == 2) {
        gp0 = (y0 + (r0 >> 5)) * 64 + x0 + (r0 & 31);
        gp1 = (y0 + (r1 >> 5)) * 64 + x0 + (r1 & 31);
    } else {
        gp0 = bx * 128 + r0;
        gp1 = bx * 128 + r1;
    }
    const ushort_t* bRow0 = bAz + (bbase + gp0) * Kb1;
    const ushort_t* bRow1 = bAz + (bbase + gp1) * Kb1;
    uint4 pfA0 = *(const uint4*)(wAz + (size_t)r0 * wstride + c0 * 8);
    uint4 pfA1 = *(const uint4*)(wAz + (size_t)r1 * wstride + c0 * 8);
    uint4 pfB0 = *(const uint4*)(bRow0 + c0 * 8);
    uint4 pfB1 = *(const uint4*)(bRow1 + c0 * 8);
    for (int ck = 0; ck < NK; ++ck) {
        __syncthreads();
        *(uint4*)(lds + r0 * 64 + SWZ(c0, r0) * 16) = pfA0;
        *(uint4*)(lds + r1 * 64 + SWZ(c0, r1) * 16) = pfA1;
        *(uint4*)(lds + 8192 + r0 * 64 + SWZ(c0, r0) * 16) = pfB0;
        *(uint4*)(lds + 8192 + r1 * 64 + SWZ(c0, r1) * 16) = pfB1;
        __syncthreads();
        if (ck + 1 < NK) {
            int k0 = (ck + 1) * 32;
            pfA0 = *(const uint4*)(wAz + (size_t)r0 * wstride + k0 + c0 * 8);
            pfA1 = *(const uint4*)(wAz + (size_t)r1 * wstride + k0 + c0 * 8);
            pfB0 = *(const uint4*)(bRow0 + k0 + c0 * 8);
            pfB1 = *(const uint4*)(bRow1 + k0 + c0 * 8);
        }
        short8 af[4];
#pragma unroll
        for (int mt = 0; mt < 4; ++mt) {
            int row = wm * 64 + mt * 16 + lo;
            af[mt] = *(const short8*)(lds + row * 64 + SWZ(quad, row) * 16);
        }
#pragma unroll
        for (int nt = 0; nt < 4; ++nt) {
            int n = wn * 64 + nt * 16 + lo;
            short8 bf = *(const short8*)(lds + 8192 + n * 64 + SWZ(quad, n) * 16);
#pragma unroll
            for (int mt = 0; mt < 4; ++mt) acc[mt][nt] = MFMA16(af[mt], bf, acc[mt][nt]);
        }
    }

    float mean = 0.f, rstd = 0.f;
    if (EP >= 2) {
        int slot = (EP == 3) ? 3 : z;
        float s0 = stats[(slot * 16 + b) * 2], s1 = stats[(slot * 16 + b) * 2 + 1];
        mean = s0 * INV_N;
        rstd = rsqrtf(fmaxf(s1 * INV_N - mean * mean, 0.f) + 1e-5f);
    }
    float lsum = 0.f, lss = 0.f;
    if (EP == 2) {
        __syncthreads();
        ushort_t* Cs = (ushort_t*)lds;
#pragma unroll
        for (int mt = 0; mt < 4; ++mt)
#pragma unroll
            for (int nt = 0; nt < 4; ++nt) {
                int oo0 = wm * 64 + mt * 16 + quad * 4;
                int pp = wn * 64 + nt * 16 + lo;
                int gp = (y0 + (pp >> 5)) * 64 + x0 + (pp & 31);
                size_t tbase = (bbase + gp) * 128 + oo0;
                ushort4 tv = *(const ushort4*)(bAz + tbase);
                ushort4 gv = *(const ushort4*)(gT + tbase);
                ushort4 bv = *(const ushort4*)(betT + tbase);
#pragma unroll
                for (int r = 0; r < 4; ++r) {
                    float v = acc[mt][nt][r] + bf2f((&bv.x)[r])
                            + (bf2f((&tv.x)[r]) - mean) * rstd * bf2f((&gv.x)[r]);
                    Cs[(oo0 + r) * 132 + pp] = f2bf(v);
                }
            }
        __syncthreads();
        if (z < 2) {
            // half0 [n][256]: full 512B rows
            for (int s = t; s < 1024; s += 256) {
                int n_l = s >> 5, fq = s & 31;
                int ypair = n_l >> 4, xp = n_l & 15;
                ushort_t tmp[8];
#pragma unroll
                for (int e = 0; e < 8; ++e) {
                    int f = fq * 8 + e;
                    int c = f >> 2, py = (f >> 1) & 1, px = f & 1;
                    tmp[e] = Cs[c * 132 + (ypair * 2 + py) * 32 + xp * 2 + px];
                }
                int n = ((y0 >> 1) + ypair) * 32 + (x0 >> 1) + xp;
                uint4 ov = {(uint_t)tmp[0] | ((uint_t)tmp[1] << 16), (uint_t)tmp[2] | ((uint_t)tmp[3] << 16),
                            (uint_t)tmp[4] | ((uint_t)tmp[5] << 16), (uint_t)tmp[6] | ((uint_t)tmp[7] << 16)};
                *(uint4*)(outp + ((size_t)(b * 1024 + n) << 8) + fq * 8) = ov;
            }
            // half1 [n][1024]: full 2KB rows
            for (int s = t; s < 1024; s += 256) {
                int n_l = s >> 7, fq = s & 127;
                ushort_t tmp[8];
#pragma unroll
                for (int e = 0; e < 8; ++e) {
                    int f = fq * 8 + e;
                    int c = f >> 4, py = (f >> 2) & 3, px = f & 3;
                    tmp[e] = Cs[(64 + c) * 132 + py * 32 + n_l * 4 + px];
                }
                int n = (y0 >> 2) * 16 + (x0 >> 2) + n_l;
                uint4 ov = {(uint_t)tmp[0] | ((uint_t)tmp[1] << 16), (uint_t)tmp[2] | ((uint_t)tmp[3] << 16),
                            (uint_t)tmp[4] | ((uint_t)tmp[5] << 16), (uint_t)tmp[6] | ((uint_t)tmp[7] << 16)};
                *(uint4*)(outp + 4194304u + ((size_t)(b * 256 + n) << 10) + fq * 8) = ov;
            }
        } else {
            // VT half0 [f=256][m=1024]
            for (int s = t; s < 2048; s += 256) {
                int f = s >> 3, j = s & 7;
                int ypair = j >> 2, xq = j & 3;
                int c = f >> 2, py = (f >> 1) & 1, px = f & 1;
                ushort_t tmp[4];
#pragma unroll
                for (int i2 = 0; i2 < 4; ++i2)
                    tmp[i2] = Cs[c * 132 + (ypair * 2 + py) * 32 + (xq * 4 + i2) * 2 + px];
                int m0 = ((y0 >> 1) + ypair) * 32 + (x0 >> 1) + xq * 4;
                uint2 ov = {(uint_t)tmp[0] | ((uint_t)tmp[1] << 16), (uint_t)tmp[2] | ((uint_t)tmp[3] << 16)};
                *(uint2*)(outp + ((size_t)(b * 256 + f) << 10) + m0) = ov;
            }
            // VT half1 [f=1024][m=256]
            for (int s = t; s < 2048; s += 256) {
                int f = s >> 1, j = s & 1;
                int c = f >> 4, py = (f >> 2) & 3, px = f & 3;
                ushort_t tmp[4];
#pragma unroll
                for (int i2 = 0; i2 < 4; ++i2)
                    tmp[i2] = Cs[(64 + c) * 132 + py * 32 + (j * 4 + i2) * 4 + px];
                int m0 = (y0 >> 2) * 16 + (x0 >> 2) + j * 4;
                uint2 ov = {(uint_t)tmp[0] | ((uint_t)tmp[1] << 16), (uint_t)tmp[2] | ((uint_t)tmp[3] << 16)};
                *(uint2*)(outp + 4194304u + ((size_t)(b * 1024 + f) << 8) + m0) = ov;
            }
        }
    } else {
#pragma unroll
        for (int mt = 0; mt < 4; ++mt)
#pragma unroll
            for (int nt = 0; nt < 4; ++nt) {
                int oo0 = wm * 64 + mt * 16 + quad * 4;
                int pp = wn * 64 + nt * 16 + lo;
                size_t tbase = (bbase + bx * 128 + pp) * 128 + oo0;
                float vv[4];
                if (EP == 0) {
#pragma unroll
                    for (int r = 0; r < 4; ++r) vv[r] = acc[mt][nt][r] + bias4.b[z][oo0 + r];
                    if (dostats) {
#pragma unroll
                        for (int r = 0; r < 4; ++r) { lsum += vv[r]; lss += vv[r] * vv[r]; }
                    }
                } else {  // EP 3
                    ushort4 tv = *(const ushort4*)(bAz + tbase);
                    ushort4 gv = *(const ushort4*)(gT + tbase);
                    ushort4 bv = *(const ushort4*)(betT + tbase);
#pragma unroll
                    for (int r = 0; r < 4; ++r)
                        vv[r] = acc[mt][nt][r] + bf2f((&bv.x)[r])
                              + (bf2f((&tv.x)[r]) - mean) * rstd * bf2f((&gv.x)[r]);
                }
                ushort4 st = {f2bf(vv[0]), f2bf(vv[1]), f2bf(vv[2]), f2bf(vv[3])};
                *(ushort4*)(outp + tbase) = st;
            }
    }
    if (EP == 0 && dostats) {
#pragma unroll
        for (int o2 = 32; o2 >= 1; o2 >>= 1) { lsum += __shfl_xor(lsum, o2); lss += __shfl_xor(lss, o2); }
        __syncthreads();
        float* red = (float*)lds;
        if (lane == 0) { red[w * 2] = lsum; red[w * 2 + 1] = lss; }
        __syncthreads();
        if (t == 0) {
            atomicAdd(&stats[(z * 16 + b) * 2], red[0] + red[2] + red[4] + red[6]);
            atomicAdd(&stats[(z * 16 + b) * 2 + 1], red[1] + red[3] + red[5] + red[7]);
        }
    }
}

// ===================== attention batched MFMA GEMM (unchanged from round 4) ===============
template <int EP>
__global__ __launch_bounds__(256) void gemm_attn(
    const ushort_t* A, size_t aBS, const ushort_t* Bm, size_t bBS,
    int Ka, int NK, float scale,
    ushort_t* sout, size_t soBS, int soNb,
    const ushort_t* xT, ushort_t* midT, float* stats)
{
    constexpr int LDSZ = (EP >= 1) ? 33792 : 16448;
    __shared__ char lds[LDSZ];
    int b = blockIdx.z, my = blockIdx.y, nx = blockIdx.x;
    int t = threadIdx.x, lane = t & 63, w = t >> 6;
    int wm = w & 1, wn = w >> 1, lo = lane & 15, quad = lane >> 4;

    f32x4 acc[4][4];
#pragma unroll
    for (int i = 0; i < 4; ++i)
#pragma unroll
        for (int j = 0; j < 4; ++j) acc[i][j] = (f32x4){0.f, 0.f, 0.f, 0.f};

    const ushort_t* Ab = A + b * aBS + (size_t)(my * 128) * Ka;
    const ushort_t* Bb = Bm + b * bBS + (size_t)(nx * 128) * Ka;
    int r0 = t >> 2, c0 = t & 3, r1 = r0 + 64;
    uint4 pfA0 = *(const uint4*)(Ab + (size_t)r0 * Ka + c0 * 8);
    uint4 pfA1 = *(const uint4*)(Ab + (size_t)r1 * Ka + c0 * 8);
    uint4 pfB0 = *(const uint4*)(Bb + (size_t)r0 * Ka + c0 * 8);
    uint4 pfB1 = *(const uint4*)(Bb + (size_t)r1 * Ka + c0 * 8);
    for (int ck = 0; ck < NK; ++ck) {
        __syncthreads();
        *(uint4*)(lds + r0 * 64 + SWZ(c0, r0) * 16) = pfA0;
        *(uint4*)(lds + r1 * 64 + SWZ(c0, r1) * 16) = pfA1;
        *(uint4*)(lds + 8192 + r0 * 64 + SWZ(c0, r0) * 16) = pfB0;
        *(uint4*)(lds + 8192 + r1 * 64 + SWZ(c0, r1) * 16) = pfB1;
        __syncthreads();
        if (ck + 1 < NK) {
            int k0 = (ck + 1) * 32;
            pfA0 = *(const uint4*)(Ab + (size_t)r0 * Ka + k0 + c0 * 8);
            pfA1 = *(const uint4*)(Ab + (size_t)r1 * Ka + k0 + c0 * 8);
            pfB0 = *(const uint4*)(Bb + (size_t)r0 * Ka + k0 + c0 * 8);
            pfB1 = *(const uint4*)(Bb + (size_t)r1 * Ka + k0 + c0 * 8);
        }
        short8 af[4];
#pragma unroll
        for (int mt = 0; mt < 4; ++mt) {
            int row = wm * 64 + mt * 16 + lo;
            af[mt] = *(const short8*)(lds + row * 64 + SWZ(quad, row) * 16);
        }
#pragma unroll
        for (int nt = 0; nt < 4; ++nt) {
            int n = wn * 64 + nt * 16 + lo;
            short8 bf = *(const short8*)(lds + 8192 + n * 64 + SWZ(quad, n) * 16);
#pragma unroll
            for (int mt = 0; mt < 4; ++mt) acc[mt][nt] = MFMA16(af[mt], bf, acc[mt][nt]);
        }
    }

    if (EP == 0) {
#pragma unroll
        for (int mt = 0; mt < 4; ++mt)
#pragma unroll
            for (int nt = 0; nt < 4; ++nt)
#pragma unroll
                for (int reg = 0; reg < 4; ++reg) {
                    int rr = my * 128 + wm * 64 + mt * 16 + quad * 4 + reg;
                    int cc = nx * 128 + wn * 64 + nt * 16 + lo;
                    sout[(size_t)b * soBS + (size_t)rr * soNb + cc] = f2bf(acc[mt][nt][reg] * scale);
                }
        return;
    }
    __syncthreads();
    ushort_t* Cs = (ushort_t*)lds;
#pragma unroll
    for (int mt = 0; mt < 4; ++mt)
#pragma unroll
        for (int nt = 0; nt < 4; ++nt)
#pragma unroll
            for (int reg = 0; reg < 4; ++reg) {
                int r_l = wm * 64 + mt * 16 + quad * 4 + reg;
                int c_l = wn * 64 + nt * 16 + lo;
                Cs[r_l * 132 + c_l] = f2bf(acc[mt][nt][reg]);
            }
    __syncthreads();
    float lsum = 0.f, lss = 0.f;
    for (int s = t; s < 4096; s += 256) {
        int sp, r_l, cbase, pybit, pxbit;
        if (EP == 1) {
            int sp_l = s >> 3, cj = s & 7;
            int y_l = sp_l >> 6, xv = sp_l & 63;
            r_l = (y_l >> 1) * 32 + (xv >> 1);
            sp = (my * 8 + y_l) * 64 + xv;
            cbase = nx * 32 + cj * 4;
            pybit = (y_l & 1) * 2 + (xv & 1);
            pxbit = 4;
        } else {
            int sp_l = s >> 1, cj = s & 1;
            int y_l = sp_l >> 6, xv = sp_l & 63;
            r_l = (y_l >> 2) * 16 + (xv >> 2);
            sp = (my * 32 + y_l) * 64 + xv;
            cbase = 64 + nx * 8 + cj * 4;
            pybit = (y_l & 3) * 4 + (xv & 3);
            pxbit = 16;
        }
        size_t base = ((size_t)(b * 4096) + sp) * 128 + cbase;
        ushort4 xv4 = *(const ushort4*)(xT + base);
        int c_l0 = (EP == 1) ? (cbase - nx * 32) * 4 + pybit : (cbase - 64 - nx * 8) * 16 + pybit;
        ushort_t o4[4];
#pragma unroll
        for (int ci = 0; ci < 4; ++ci) {
            float vm = bf2f(Cs[r_l * 132 + c_l0 + ci * pxbit]) + bf2f((&xv4.x)[ci]);
            o4[ci] = f2bf(vm);
            lsum += vm; lss += vm * vm;
        }
        ushort4 st = {o4[0], o4[1], o4[2], o4[3]};
        *(ushort4*)(midT + base) = st;
    }
#pragma unroll
    for (int o2 = 32; o2 >= 1; o2 >>= 1) { lsum += __shfl_xor(lsum, o2); lss += __shfl_xor(lss, o2); }
    __syncthreads();
    float* red = (float*)lds;
    if (lane == 0) { red[w * 2] = lsum; red[w * 2 + 1] = lss; }
    __syncthreads();
    if (t == 0) {
        atomicAdd(&stats[(3 * 16 + b) * 2], red[0] + red[2] + red[4] + red[6]);
        atomicAdd(&stats[(3 * 16 + b) * 2 + 1], red[1] + red[3] + red[5] + red[7]);
    }
}

// ===================== softmax (in-place bf16 S -> P) =====================
__global__ __launch_bounds__(256) void softmax_k(ushort_t* SP)
{
    int wid = blockIdx.x * 4 + (threadIdx.x >> 6);
    int lane = threadIdx.x & 63;
    ushort_t* row;
    int PL;
    if (wid < 16384) { row = SP + ((size_t)wid << 10); PL = 16; }
    else { int r2 = wid - 16384; row = SP + 16777216u + ((size_t)r2 << 8); PL = 4; }
    float v[16];
    float mx = -1e30f;
    for (int i = 0; i < PL; ++i) { v[i] = bf2f(row[lane + (i << 6)]); mx = fmaxf(mx, v[i]); }
#pragma unroll
    for (int o = 32; o >= 1; o >>= 1) mx = fmaxf(mx, __shfl_xor(mx, o));
    float sum = 0.f;
    for (int i = 0; i < PL; ++i) { v[i] = __expf(v[i] - mx); sum += v[i]; }
#pragma unroll
    for (int o = 32; o >= 1; o >>= 1) sum += __shfl_xor(sum, o);
    float inv = 1.f / sum;
    for (int i = 0; i < PL; ++i) row[lane + (i << 6)] = f2bf(v[i] * inv);
}

// ===================== conv3x3 dual (tanh DIL1 / gelu DIL2 via z) =====================
__global__ __launch_bounds__(256) void conv3x3_dual(
    const ushort_t* __restrict__ inT, const ushort_t* __restrict__ wtA, const ushort_t* __restrict__ wtB,
    const float* __restrict__ biasA, const float* __restrict__ biasB,
    ushort_t* __restrict__ outA, ushort_t* __restrict__ outB)
{
    __shared__ char lds[24576 + 8 * 68 * 64];
    char* Braw = lds + 24576;
    int b = blockIdx.y, z = blockIdx.z;
    int dil = 1 + z;
    int NRr = 2 + 2 * dil;
    const ushort_t* wt = z ? wtB : wtA;
    const float* bias = z ? biasB : biasA;
    ushort_t* out = z ? outB : outA;
    int y0 = blockIdx.x * 2;
    int t = threadIdx.x, lane = t & 63, w = t >> 6;
    int wm = w & 1, wn = w >> 1, lo = lane & 15, quad = lane >> 4;

    f32x4 acc[4][4];
#pragma unroll
    for (int i = 0; i < 4; ++i)
#pragma unroll
        for (int j = 0; j < 4; ++j) acc[i][j] = (f32x4){0.f, 0.f, 0.f, 0.f};

    for (int cc = 0; cc < 4; ++cc) {
        __syncthreads();
        int NSLOT = NRr * 68 * 4;
        for (int s = t; s < NSLOT; s += 256) {
            int c4 = s & 3;
            int pr = s >> 2;
            int xx = pr % 68, rr = pr / 68;
            int ys = y0 - dil + rr;
            int ix = xx - dil;
            uint4 v = {0u, 0u, 0u, 0u};
            if (ys >= 0 && ys < 64 && (unsigned)ix < 64u)
                v = *(const uint4*)(inT + (size_t)(b * 4096 + ys * 64 + ix) * 128 + cc * 32 + c4 * 8);
            *(uint4*)(Braw + pr * 64 + SWZ(c4, pr) * 16) = v;
        }
        for (int ky = 0; ky < 3; ++ky) {
            __syncthreads();
            for (int s = t; s < 1536; s += 256) {
                int kx = s >> 9, r = (s >> 2) & 127, c = s & 3;
                uint4 v = *(const uint4*)(wt + ((size_t)((ky * 3 + kx) * 128 + r) << 7) + cc * 32 + c * 8);
                *(uint4*)(lds + kx * 8192 + r * 64 + SWZ(c, r) * 16) = v;
            }
            __syncthreads();
#pragma unroll
            for (int kx = 0; kx < 3; ++kx) {
                short8 af[4];
#pragma unroll
                for (int mt = 0; mt < 4; ++mt) {
                    int row = wm * 64 + mt * 16 + lo;
                    af[mt] = *(const short8*)(lds + kx * 8192 + row * 64 + SWZ(quad, row) * 16);
                }
#pragma unroll
                for (int nt = 0; nt < 4; ++nt) {
                    int n = wn * 64 + nt * 16 + lo;
                    int pr = ((n >> 6) + ky * dil) * 68 + (n & 63) + kx * dil;
                    short8 bf = *(const short8*)(Braw + pr * 64 + SWZ(quad, pr) * 16);
#pragma unroll
                    for (int mt = 0; mt < 4; ++mt) acc[mt][nt] = MFMA16(af[mt], bf, acc[mt][nt]);
                }
            }
        }
    }
#pragma unroll
    for (int mt = 0; mt < 4; ++mt)
#pragma unroll
        for (int nt = 0; nt < 4; ++nt) {
            int oo0 = wm * 64 + mt * 16 + quad * 4;
            int pp = wn * 64 + nt * 16 + lo;
            int sp = (y0 + (pp >> 6)) * 64 + (pp & 63);
            size_t tbase = ((size_t)(b * 4096) + sp) * 128 + oo0;
            ushort4 st;
#pragma unroll
            for (int r = 0; r < 4; ++r) {
                float v = acc[mt][nt][r] + bias[oo0 + r];
                if (z == 0) v = tanhf(v);
                else        v = 0.5f * v * (1.f + erff(v * 0.70710678118654752f));
                (&st.x)[r] = f2bf(v);
            }
            *(ushort4*)(out + tbase) = st;
        }
}

// ===================== conv3x3 final: midT*g3T + conv(tT) -> f32 [b][c][p] ==============
__global__ __launch_bounds__(256) void conv3x3_final(
    const ushort_t* __restrict__ inT, const ushort_t* __restrict__ wt, const float* __restrict__ bias,
    float* __restrict__ out, const ushort_t* __restrict__ midT, const ushort_t* __restrict__ g3T)
{
    __shared__ char lds[24576 + 4 * 68 * 64];
    char* Braw = lds + 24576;
    int b = blockIdx.y;
    int y0 = blockIdx.x * 2;
    int t = threadIdx.x, lane = t & 63, w = t >> 6;
    int wm = w & 1, wn = w >> 1, lo = lane & 15, quad = lane >> 4;

    f32x4 acc[4][4];
#pragma unroll
    for (int i = 0; i < 4; ++i)
#pragma unroll
        for (int j = 0; j < 4; ++j) acc[i][j] = (f32x4){0.f, 0.f, 0.f, 0.f};

    for (int cc = 0; cc < 4; ++cc) {
        __syncthreads();
        for (int s = t; s < 1088; s += 256) {
            int c4 = s & 3;
            int pr = s >> 2;
            int xx = pr % 68, rr = pr / 68;
            int ys = y0 - 1 + rr;
            int ix = xx - 1;
            uint4 v = {0u, 0u, 0u, 0u};
            if (ys >= 0 && ys < 64 && (unsigned)ix < 64u)
                v = *(const uint4*)(inT + (size_t)(b * 4096 + ys * 64 + ix) * 128 + cc * 32 + c4 * 8);
            *(uint4*)(Braw + pr * 64 + SWZ(c4, pr) * 16) = v;
        }
        for (int ky = 0; ky < 3; ++ky) {
            __syncthreads();
            for (int s = t; s < 1536; s += 256) {
                int kx = s >> 9, r = (s >> 2) & 127, c = s & 3;
                uint4 v = *(const uint4*)(wt + ((size_t)((ky * 3 + kx) * 128 + r) << 7) + cc * 32 + c * 8);
                *(uint4*)(lds + kx * 8192 + r * 64 + SWZ(c, r) * 16) = v;
            }
            __syncthreads();
#pragma unroll
            for (int kx = 0; kx < 3; ++kx) {
                short8 af[4];
#pragma unroll
                for (int mt = 0; mt < 4; ++mt) {
                    int row = wm * 64 + mt * 16 + lo;
                    af[mt] = *(const short8*)(lds + kx * 8192 + row * 64 + SWZ(quad, row) * 16);
                }
#pragma unroll
                for (int nt = 0; nt < 4; ++nt) {
                    int n = wn * 64 + nt * 16 + lo;
                    int pr = ((n >> 6) + ky) * 68 + (n & 63) + kx;
                    short8 bf = *(const short8*)(Braw + pr * 64 + SWZ(quad, pr) * 16);
#pragma unroll
                    for (int mt = 0; mt < 4; ++mt) acc[mt][nt] = MFMA16(af[mt], bf, acc[mt][nt]);
                }
            }
        }
    }
#pragma unroll
    for (int mt = 0; mt < 4; ++mt)
#pragma unroll
        for (int nt = 0; nt < 4; ++nt) {
            int oo0 = wm * 64 + mt * 16 + quad * 4;
            int pp = wn * 64 + nt * 16 + lo;
            int sp = (y0 + (pp >> 6)) * 64 + (pp & 63);
            size_t tbase = ((size_t)(b * 4096) + sp) * 128 + oo0;
            ushort4 mv = *(const ushort4*)(midT + tbase);
            ushort4 gv = *(const ushort4*)(g3T + tbase);
#pragma unroll
            for (int r = 0; r < 4; ++r) {
                int oo = oo0 + r;
                size_t off = ((size_t)(b * 128 + oo) << 12) + sp;
                out[off] = bf2f((&mv.x)[r]) * bf2f((&gv.x)[r]) + acc[mt][nt][r] + bias[oo];
            }
        }
}

// ===================== launch =====================
extern "C" void kernel_launch(void* const* d_in, const int* in_sizes, int n_in,
                              void* d_out, int out_size, void* d_ws, size_t ws_size,
                              hipStream_t stream)
{
    const float* x    = (const float*)d_in[0];
    const float* edge = (const float*)d_in[1];
    const float* seg  = (const float*)d_in[2];
    const float* pe   = (const float*)d_in[3];
    const float* ps   = (const float*)d_in[4];
    const float* q_w  = (const float*)d_in[5];  const float* q_b  = (const float*)d_in[6];
    const float* k_w  = (const float*)d_in[7];  const float* k_b  = (const float*)d_in[8];
    const float* v_w  = (const float*)d_in[9];  const float* v_b  = (const float*)d_in[10];
    const float* d1_ew = (const float*)d_in[11]; const float* d1_eb = (const float*)d_in[12];
    const float* d1_sw = (const float*)d_in[13]; const float* d1_sb = (const float*)d_in[14];
    const float* d1_bw = (const float*)d_in[15]; const float* d1_bb = (const float*)d_in[16];
    const float* d2_ew = (const float*)d_in[17]; const float* d2_eb = (const float*)d_in[18];
    const float* d2_sw = (const float*)d_in[19]; const float* d2_sb = (const float*)d_in[20];
    const float* d2_bw = (const float*)d_in[21]; const float* d2_bb = (const float*)d_in[22];
    const float* sc_w  = (const float*)d_in[23]; const float* sc_b  = (const float*)d_in[24];
    const float* bi1_w = (const float*)d_in[25]; const float* bi1_b = (const float*)d_in[26];
    const float* bi2_w = (const float*)d_in[27]; const float* bi2_b = (const float*)d_in[28];

    char* ws = (char*)d_ws;
    ushort_t* wb = (ushort_t*)ws;                         // 1,327,360
    ushort_t* wc = (ushort_t*)(ws + 1327360);             // 294,912
    float* bc    = (float*)(ws + 1622272);                // 2,048
    float* stats = (float*)(ws + 1624320);                // 512
    char* RA = ws + 1703936;                              // 37,748,736: auxT -> SP
    char* RB = RA + 37748736;                             // 16,777,216: xT
    char* RC = RB + 16777216;                             // 50,331,648: q0T/k0T/v0T -> midT+oT
    char* RD = RC + 50331648;                             // 16,777,216: g1 -> g3
    char* RE = RD + 16777216;                             // 16,777,216: betA1
    char* RF = RE + 16777216;                             // 16,777,216: g2
    char* RG = RF + 16777216;                             // 16,777,216: betA2
    char* RH = RG + 16777216;                             // 33,554,432: Qp,Kp
    char* RI = RH + 33554432;                             // 16,777,216: VT -> tT

    ushort_t* auxT = (ushort_t*)RA;
    ushort_t* SP0  = (ushort_t*)RA;
    ushort_t* xT   = (ushort_t*)RB;
    ushort_t* q0T  = (ushort_t*)RC;
    ushort_t* midT = (ushort_t*)RC;
    ushort_t* oT   = (ushort_t*)(RC + 16777216);
    ushort_t* g1   = (ushort_t*)RD;
    ushort_t* g3   = (ushort_t*)RD;
    ushort_t* betA1= (ushort_t*)RE;
    ushort_t* g2   = (ushort_t*)RF;
    ushort_t* betA2= (ushort_t*)RG;
    ushort_t* Qp   = (ushort_t*)RH;
    ushort_t* Kp   = Qp + 8388608;
    ushort_t* VT   = (ushort_t*)RI;
    ushort_t* tT   = (ushort_t*)RI;
    const size_t ZB = 8388608;

    dim3 blk(256);

    hipMemsetAsync(stats, 0, 512, stream);
    prep_w<<<2592, blk, 0, stream>>>(wb, q_w, k_w, v_w, d1_ew, d2_ew, d1_sw, d2_sw, d1_bw, d2_bw, sc_w, bi1_w, bi2_w);
    combine_bias<<<1, 512, 0, stream>>>(bc, d1_sw, d1_bw, d2_sw, d2_bw, d1_eb, d2_eb, d1_sb, d1_bb, d2_sb, d2_bb);
    combine_w<<<dim3(9, 4), blk, 0, stream>>>(wc, wb);
    transp_x<<<dim3(64, 16), blk, 0, stream>>>(x, xT);
    transp_aux<<<dim3(64, 16), blk, 0, stream>>>(edge, seg, pe, ps, auxT);

    // aux mega-GEMM: g1, betA1, g2, betA2
    gemm_conv<0><<<dim3(32, 16, 4), blk, 0, stream>>>(auxT, 288, 0, wc, 288, 1, 9,
        B4{{bc, bc + 128, bc + 256, bc + 384}}, P4{{g1, betA1, g2, betA2}}, nullptr, nullptr, stats, 0);
    // qkv (+LN stats slots 0..2)
    gemm_conv<0><<<dim3(32, 16, 3), blk, 0, stream>>>(xT, 128, 0, wb, 128, 1, 4,
        B4{{q_b, k_b, v_b, nullptr}}, P4{{q0T, q0T + ZB, q0T + 2 * ZB, nullptr}}, nullptr, nullptr, stats, 1);
    // ADN1 -> Qp, Kp, VT (K=128 now)
    gemm_conv<2><<<dim3(32, 16, 3), blk, 0, stream>>>(q0T, 128, ZB, wb + 155648, 256, 0, 4,
        B4{{nullptr, nullptr, nullptr, nullptr}}, P4{{Qp, Kp, VT, nullptr}}, g1, betA1, stats, 0);

    // attention
    gemm_attn<0><<<dim3(8, 8, 16), blk, 0, stream>>>(Qp, 262144, Kp, 262144, 256, 8, 0.0625f,
        SP0, 1048576, 1024, nullptr, nullptr, stats);
    gemm_attn<0><<<dim3(2, 2, 16), blk, 0, stream>>>(Qp + 4194304, 262144, Kp + 4194304, 262144, 1024, 32, 0.03125f,
        SP0 + 16777216, 65536, 256, nullptr, nullptr, stats);
    softmax_k<<<5120, blk, 0, stream>>>(SP0);
    gemm_attn<1><<<dim3(2, 8, 16), blk, 0, stream>>>(SP0, 1048576, VT, 262144, 1024, 32, 1.f,
        nullptr, 0, 0, xT, midT, stats);
    gemm_attn<2><<<dim3(8, 2, 16), blk, 0, stream>>>(SP0 + 16777216, 65536, VT + 4194304, 262144, 256, 8, 1.f,
        nullptr, 0, 0, xT, midT, stats);

    // ADN2 -> oT (K=128)
    gemm_conv<3><<<dim3(32, 16, 1), blk, 0, stream>>>(midT, 128, 0, wb + 155648 + 32768, 256, 0, 4,
        B4{{nullptr, nullptr, nullptr, nullptr}}, P4{{oT, nullptr, nullptr, nullptr}}, g2, betA2, stats, 0);

    // conv3x3 tail: tanh+gelu fused launch, then final
    conv3x3_dual<<<dim3(32, 16, 2), blk, 0, stream>>>(oT, wb + 221184, wb + 368640, sc_b, bi1_b, g3, tT);
    conv3x3_final<<<dim3(32, 16), blk, 0, stream>>>(tT, wb + 516096, bi2_b, (float*)d_out, midT, g3);
}